// Round 1
// baseline (3076.387 us; speedup 1.0000x reference)
//
#include <hip/hip_runtime.h>
#include <cmath>

#define SCALE_F 0.088388347648318447f  // 1/sqrt(128)

// ---------------- GEMM: C[M,N] = A[M,K] @ W[N,K]^T  (f32) ----------------
__global__ __launch_bounds__(256, 2) void gemm_bt_f32(
    const float* __restrict__ A, const float* __restrict__ W,
    float* __restrict__ C, int M, int N, int K)
{
    __shared__ float As[16][132];
    __shared__ float Ws[16][132];
    const int tid = threadIdx.x;
    const int tx = tid & 15, ty = tid >> 4;
    const int bm = blockIdx.y * 128, bn = blockIdx.x * 128;
    const int lr = tid >> 1;          // 0..127 row in tile
    const int lk = (tid & 1) * 8;     // 0 or 8
    const float* Ap = A + (size_t)(bm + lr) * K + lk;
    const float* Wp = W + (size_t)(bn + lr) * K + lk;

    float acc[8][8];
#pragma unroll
    for (int i = 0; i < 8; ++i)
#pragma unroll
        for (int j = 0; j < 8; ++j) acc[i][j] = 0.0f;

    for (int k0 = 0; k0 < K; k0 += 16) {
        const float4 a0 = *(const float4*)(Ap + k0);
        const float4 a1 = *(const float4*)(Ap + k0 + 4);
        const float4 w0 = *(const float4*)(Wp + k0);
        const float4 w1 = *(const float4*)(Wp + k0 + 4);
        __syncthreads();
        As[lk + 0][lr] = a0.x; As[lk + 1][lr] = a0.y;
        As[lk + 2][lr] = a0.z; As[lk + 3][lr] = a0.w;
        As[lk + 4][lr] = a1.x; As[lk + 5][lr] = a1.y;
        As[lk + 6][lr] = a1.z; As[lk + 7][lr] = a1.w;
        Ws[lk + 0][lr] = w0.x; Ws[lk + 1][lr] = w0.y;
        Ws[lk + 2][lr] = w0.z; Ws[lk + 3][lr] = w0.w;
        Ws[lk + 4][lr] = w1.x; Ws[lk + 5][lr] = w1.y;
        Ws[lk + 6][lr] = w1.z; Ws[lk + 7][lr] = w1.w;
        __syncthreads();
#pragma unroll
        for (int kk = 0; kk < 16; ++kk) {
            float av[8], wv[8];
            *(float4*)&av[0] = *(const float4*)&As[kk][ty * 8];
            *(float4*)&av[4] = *(const float4*)&As[kk][ty * 8 + 4];
            *(float4*)&wv[0] = *(const float4*)&Ws[kk][tx * 8];
            *(float4*)&wv[4] = *(const float4*)&Ws[kk][tx * 8 + 4];
#pragma unroll
            for (int i = 0; i < 8; ++i)
#pragma unroll
                for (int j = 0; j < 8; ++j)
                    acc[i][j] = fmaf(av[i], wv[j], acc[i][j]);
        }
    }
#pragma unroll
    for (int i = 0; i < 8; ++i) {
        float* cp = C + (size_t)(bm + ty * 8 + i) * N + bn + tx * 8;
        *(float4*)cp = make_float4(acc[i][0], acc[i][1], acc[i][2], acc[i][3]);
        *(float4*)(cp + 4) = make_float4(acc[i][4], acc[i][5], acc[i][6], acc[i][7]);
    }
}

// ---------------- RoPE in-place on [4096, 2048] (pairs adjacent) ----------------
__global__ __launch_bounds__(256) void rope_f32(
    float* __restrict__ X, const float* __restrict__ cs, const float* __restrict__ sn)
{
    const int p = blockIdx.x * 256 + threadIdx.x;  // pair index, total 4194304
    const int r = p >> 10;        // row in [0,4096)
    const int c = p & 1023;       // pair-col in [0,1024): head h = c>>6, i = c&63
    const int i = c & 63;
    const int t = r & 2047;
    float2 x = *(float2*)&X[(size_t)r * 2048 + c * 2];
    const float co = cs[t * 64 + i];
    const float si = sn[t * 64 + i];
    float2 y;
    y.x = x.x * co - x.y * si;
    y.y = x.y * co + x.x * si;
    *(float2*)&X[(size_t)r * 2048 + c * 2] = y;
}

// ---------------- Flash attention f32: QB=64, SB=64, 4x4 / 4x8 micro ----------------
__global__ __launch_bounds__(256, 1) void flash_attn_f32(
    const float* __restrict__ Qg, const float* __restrict__ Kg,
    const float* __restrict__ Vg, float* __restrict__ Og)
{
    __shared__ __align__(16) float Qt[128][66];   // [d][r], Q pre-scaled
    __shared__ __align__(16) float Kt[128][66];   // [d][s]
    __shared__ __align__(16) float Vs[64][132];   // [s][d]
    __shared__ __align__(16) float Pt[64][68];    // [s][r]  scores then probs
    __shared__ float m_row[64], l_row[64], c_row[64];

    const int tid = threadIdx.x;
    const int tx = tid & 15, ty = tid >> 4;
    const int qt = blockIdx.x, bh = blockIdx.y;
    const int b = bh >> 4, h = bh & 15;
    const size_t qbase = ((size_t)(b * 2048 + qt * 64)) * 2048 + h * 128;
    const size_t kbase = ((size_t)(b * 2048)) * 2048 + h * 128;

    const int sr = tid >> 2;          // 0..63 (staging row)
    const int sd = (tid & 3) * 4;     // 0,4,8,12

#pragma unroll
    for (int u = 0; u < 8; ++u) {
        const int d = sd + u * 16;
        const float4 q = *(const float4*)&Qg[qbase + (size_t)sr * 2048 + d];
        Qt[d + 0][sr] = q.x * SCALE_F;
        Qt[d + 1][sr] = q.y * SCALE_F;
        Qt[d + 2][sr] = q.z * SCALE_F;
        Qt[d + 3][sr] = q.w * SCALE_F;
    }
    if (tid < 64) { m_row[tid] = -1.0e30f; l_row[tid] = 0.0f; }

    float o[4][8];
#pragma unroll
    for (int i = 0; i < 4; ++i)
#pragma unroll
        for (int j = 0; j < 8; ++j) o[i][j] = 0.0f;

    for (int st = 0; st < 2048; st += 64) {
        // stage K (d-major) + V (s-major)
#pragma unroll
        for (int u = 0; u < 8; ++u) {
            const int d = sd + u * 16;
            const size_t g = kbase + (size_t)(st + sr) * 2048 + d;
            const float4 k = *(const float4*)&Kg[g];
            const float4 v = *(const float4*)&Vg[g];
            Kt[d + 0][sr] = k.x; Kt[d + 1][sr] = k.y;
            Kt[d + 2][sr] = k.z; Kt[d + 3][sr] = k.w;
            *(float4*)&Vs[sr][d] = v;
        }
        __syncthreads();

        // phase 1: scores 64x64, thread computes rows ty*4.., cols tx*4..
        float sc[4][4];
#pragma unroll
        for (int i = 0; i < 4; ++i)
#pragma unroll
            for (int j = 0; j < 4; ++j) sc[i][j] = 0.0f;

#pragma unroll 4
        for (int d = 0; d < 128; ++d) {
            const float2 qa = *(const float2*)&Qt[d][ty * 4];
            const float2 qb = *(const float2*)&Qt[d][ty * 4 + 2];
            const float2 ka = *(const float2*)&Kt[d][tx * 4];
            const float2 kb = *(const float2*)&Kt[d][tx * 4 + 2];
            const float qv[4] = {qa.x, qa.y, qb.x, qb.y};
            const float kv[4] = {ka.x, ka.y, kb.x, kb.y};
#pragma unroll
            for (int i = 0; i < 4; ++i)
#pragma unroll
                for (int j = 0; j < 4; ++j)
                    sc[i][j] = fmaf(qv[i], kv[j], sc[i][j]);
        }
#pragma unroll
        for (int i = 0; i < 4; ++i)
#pragma unroll
            for (int j = 0; j < 4; ++j)
                Pt[tx * 4 + j][ty * 4 + i] = sc[i][j];
        __syncthreads();

        // phase 2: online softmax (4 lanes per row)
        {
            const int r = tid >> 2;
            const int seg = tid & 3;
            float vals[16];
            float mx = -1.0e30f;
#pragma unroll
            for (int c2 = 0; c2 < 16; ++c2) {
                vals[c2] = Pt[seg * 16 + c2][r];
                mx = fmaxf(mx, vals[c2]);
            }
            mx = fmaxf(mx, __shfl_xor(mx, 1));
            mx = fmaxf(mx, __shfl_xor(mx, 2));
            const float m_old = m_row[r];
            const float m_new = fmaxf(m_old, mx);
            float sum = 0.0f;
#pragma unroll
            for (int c2 = 0; c2 < 16; ++c2) {
                const float pexp = __expf(vals[c2] - m_new);
                Pt[seg * 16 + c2][r] = pexp;
                sum += pexp;
            }
            sum += __shfl_xor(sum, 1);
            sum += __shfl_xor(sum, 2);
            if (seg == 0) {
                const float cc = __expf(m_old - m_new);
                c_row[r] = cc;
                m_row[r] = m_new;
                l_row[r] = l_row[r] * cc + sum;
            }
        }
        __syncthreads();

        // phase 3: O = c*O + P^T-slice @ V; thread owns rows ty*4.., dims tx*8..
        {
#pragma unroll
            for (int i = 0; i < 4; ++i) {
                const float cc = c_row[ty * 4 + i];
#pragma unroll
                for (int j = 0; j < 8; ++j) o[i][j] *= cc;
            }
#pragma unroll 4
            for (int s = 0; s < 64; ++s) {
                const float4 p4 = *(const float4*)&Pt[s][ty * 4];
                const float4 va = *(const float4*)&Vs[s][tx * 8];
                const float4 vb = *(const float4*)&Vs[s][tx * 8 + 4];
                const float pv[4] = {p4.x, p4.y, p4.z, p4.w};
                const float vv[8] = {va.x, va.y, va.z, va.w, vb.x, vb.y, vb.z, vb.w};
#pragma unroll
                for (int i = 0; i < 4; ++i)
#pragma unroll
                    for (int j = 0; j < 8; ++j)
                        o[i][j] = fmaf(pv[i], vv[j], o[i][j]);
            }
        }
        __syncthreads();
    }

    // epilogue: normalize and write ctx in [b,t,h,d] (merged heads) layout
#pragma unroll
    for (int i = 0; i < 4; ++i) {
        const int r = ty * 4 + i;
        const float inv = 1.0f / l_row[r];
        float* op = Og + qbase + (size_t)r * 2048 + tx * 8;
        *(float4*)op = make_float4(o[i][0] * inv, o[i][1] * inv, o[i][2] * inv, o[i][3] * inv);
        *(float4*)(op + 4) = make_float4(o[i][4] * inv, o[i][5] * inv, o[i][6] * inv, o[i][7] * inv);
    }
}

extern "C" void kernel_launch(void* const* d_in, const int* in_sizes, int n_in,
                              void* d_out, int out_size, void* d_ws, size_t ws_size,
                              hipStream_t stream) {
    const float* hs = (const float*)d_in[0];   // [2,2048,2048]
    const float* es = (const float*)d_in[1];   // [2,2048,2048]
    const float* Wq = (const float*)d_in[2];   // [2048,2048]
    const float* Wk = (const float*)d_in[3];
    const float* Wv = (const float*)d_in[4];
    const float* Wo = (const float*)d_in[5];
    const float* cq = (const float*)d_in[6];   // [2048,64]
    const float* sq = (const float*)d_in[7];
    const float* ck = (const float*)d_in[8];
    const float* sk = (const float*)d_in[9];
    float* out = (float*)d_out;

    float* Q  = (float*)d_ws;            // 4096x2048
    float* K  = Q + 8388608;
    float* V  = K + 8388608;
    float* Cx = V + 8388608;

    dim3 gG(16, 32), tB(256);
    gemm_bt_f32<<<gG, tB, 0, stream>>>(hs, Wq, Q, 4096, 2048, 2048);
    gemm_bt_f32<<<gG, tB, 0, stream>>>(es, Wk, K, 4096, 2048, 2048);
    gemm_bt_f32<<<gG, tB, 0, stream>>>(es, Wv, V, 4096, 2048, 2048);
    rope_f32<<<dim3(16384), tB, 0, stream>>>(Q, cq, sq);
    rope_f32<<<dim3(16384), tB, 0, stream>>>(K, ck, sk);
    flash_attn_f32<<<dim3(32, 32), tB, 0, stream>>>(Q, K, V, Cx);
    gemm_bt_f32<<<gG, tB, 0, stream>>>(Cx, Wo, out, 4096, 2048, 2048);
}

// Round 2
// 359.057 us; speedup vs baseline: 8.5680x; 8.5680x over previous
//
#include <hip/hip_runtime.h>
#include <cmath>

#define SCALE_F 0.088388347648318447f  // 1/sqrt(128)

typedef _Float16 f16;
typedef _Float16 f16x8 __attribute__((ext_vector_type(8)));
typedef float f32x4 __attribute__((ext_vector_type(4)));

#define MFMA16(a, b, c) __builtin_amdgcn_mfma_f32_16x16x32_f16(a, b, c, 0, 0, 0)

__device__ __forceinline__ void gl2lds16(const f16* g, f16* l) {
    __builtin_amdgcn_global_load_lds(
        (const __attribute__((address_space(1))) unsigned int*)g,
        (__attribute__((address_space(3))) unsigned int*)l, 16, 0, 0);
}

// ---------------- f32 -> f16 convert (8 elems/thread) ----------------
__global__ __launch_bounds__(256) void cvt_f32_f16(
    const float* __restrict__ in, f16* __restrict__ out, int n8)
{
    const int i = blockIdx.x * 256 + threadIdx.x;
    if (i >= n8) return;
    const float4* p = (const float4*)in + (size_t)i * 2;
    const float4 a = p[0], b = p[1];
    f16x8 o = {(f16)a.x, (f16)a.y, (f16)a.z, (f16)a.w,
               (f16)b.x, (f16)b.y, (f16)b.z, (f16)b.w};
    *(f16x8*)(out + (size_t)i * 8) = o;
}

// ---------------- GEMM: C[M,N] = A[M,K] @ W[N,K]^T, fp16 in, MFMA ----------------
// OUT_MODE: 0 = f16 [M][N], 1 = f16 transposed per-batch ([b*2048+n][m&2047]), 2 = f32 [M][N]
template <int OUT_MODE>
__global__ __launch_bounds__(256, 2) void gemm16(
    const f16* __restrict__ A, const f16* __restrict__ W,
    void* __restrict__ Cv, int M, int N, int K)
{
    __shared__ __align__(16) f16 Al[128 * 64];
    __shared__ __align__(16) f16 Bl[128 * 64];
    const int tid = threadIdx.x;
    const int l = tid & 63, w = tid >> 6;
    const int wr = w >> 1, wc = w & 1;

    // XCD-bijective swizzle (gridDim.x % 8 == 0)
    const int nwg = gridDim.x, cpx = nwg >> 3;
    const int bid = blockIdx.x;
    const int swz = (bid & 7) * cpx + (bid >> 3);
    const int nbn = N >> 7;
    const int bm = (swz / nbn) * 128, bn = (swz % nbn) * 128;

    f32x4 acc[4][4];
#pragma unroll
    for (int i = 0; i < 4; ++i)
#pragma unroll
        for (int j = 0; j < 4; ++j) acc[i][j] = (f32x4){0.f, 0.f, 0.f, 0.f};

    const int srow = tid >> 3;          // 0..31 (staging row base)
    const int sg = tid & 7;             // phys granule 0..7

    for (int k0 = 0; k0 < K; k0 += 64) {
        __syncthreads();
#pragma unroll
        for (int i = 0; i < 4; ++i) {
            const int row = i * 32 + srow;
            const int lg = sg ^ (row & 7);
            gl2lds16(A + (size_t)(bm + row) * K + k0 + lg * 8, Al + row * 64 + sg * 8);
            gl2lds16(W + (size_t)(bn + row) * K + k0 + lg * 8, Bl + row * 64 + sg * 8);
        }
        __syncthreads();
#pragma unroll
        for (int kk = 0; kk < 2; ++kk) {
            f16x8 a[4], b[4];
            const int g = kk * 4 + (l >> 4);
#pragma unroll
            for (int m = 0; m < 4; ++m) {
                const int row = wr * 64 + m * 16 + (l & 15);
                a[m] = *(const f16x8*)(Al + row * 64 + (g ^ (row & 7)) * 8);
            }
#pragma unroll
            for (int n = 0; n < 4; ++n) {
                const int row = wc * 64 + n * 16 + (l & 15);
                b[n] = *(const f16x8*)(Bl + row * 64 + (g ^ (row & 7)) * 8);
            }
#pragma unroll
            for (int m = 0; m < 4; ++m)
#pragma unroll
                for (int n = 0; n < 4; ++n)
                    acc[m][n] = MFMA16(a[m], b[n], acc[m][n]);
        }
    }

#pragma unroll
    for (int m = 0; m < 4; ++m)
#pragma unroll
        for (int n = 0; n < 4; ++n)
#pragma unroll
            for (int j = 0; j < 4; ++j) {
                const int r = bm + wr * 64 + m * 16 + ((l >> 4) << 2) + j;
                const int c = bn + wc * 64 + n * 16 + (l & 15);
                if (OUT_MODE == 0) {
                    ((f16*)Cv)[(size_t)r * N + c] = (f16)acc[m][n][j];
                } else if (OUT_MODE == 1) {
                    ((f16*)Cv)[(size_t)((r >> 11) * 2048 + c) * 2048 + (r & 2047)] = (f16)acc[m][n][j];
                } else {
                    ((float*)Cv)[(size_t)r * N + c] = acc[m][n][j];
                }
            }
}

// ---------------- RoPE in-place on f16 [4096][2048], pairs adjacent ----------------
__global__ __launch_bounds__(256) void rope16(
    f16* __restrict__ X, const float* __restrict__ cs, const float* __restrict__ sn)
{
    const int idx = blockIdx.x * 256 + threadIdx.x;  // chunk of 8 halfs (4 pairs)
    const int r = idx >> 8;          // row 0..4095
    const int c8 = idx & 255;        // chunk within row
    const int t = r & 2047;
    const int i0 = (c8 * 4) & 63;    // pair index within head (4-aligned, no head crossing)
    const float4 cc = *(const float4*)&cs[t * 64 + i0];
    const float4 ss = *(const float4*)&sn[t * 64 + i0];
    f16* p = X + (size_t)r * 2048 + c8 * 8;
    f16x8 x = *(f16x8*)p;
    const float c0[4] = {cc.x, cc.y, cc.z, cc.w};
    const float s0[4] = {ss.x, ss.y, ss.z, ss.w};
    f16x8 y;
#pragma unroll
    for (int k = 0; k < 4; ++k) {
        const float x0 = (float)x[2 * k], x1 = (float)x[2 * k + 1];
        y[2 * k]     = (f16)(x0 * c0[k] - x1 * s0[k]);
        y[2 * k + 1] = (f16)(x1 * c0[k] + x0 * s0[k]);
    }
    *(f16x8*)p = y;
}

// ---------------- Flash attention fp16 MFMA: 4 waves x 16 q-rows, SB=64 ----------------
__global__ __launch_bounds__(256, 2) void attn16(
    const f16* __restrict__ Qg, const f16* __restrict__ Kg,
    const f16* __restrict__ Vt, f16* __restrict__ Og)
{
    __shared__ __align__(16) f16 Kl[64 * 128];   // [s][d], 16 granules/row, swz ^(s&15)
    __shared__ __align__(16) f16 Vl[128 * 64];   // [d][s], 8 granules/row, swz ^(d&7)
    __shared__ __align__(16) f16 Pl[4][16 * 64]; // per-wave [q][s], swz ^(q&7)

    const int tid = threadIdx.x;
    const int l = tid & 63, w = tid >> 6;

    // XCD swizzle over flat grid (1024 blocks): keep one (b,h)'s q-tiles on one XCD
    const int bid = blockIdx.x;
    const int swz = (bid & 7) * 128 + (bid >> 3);
    const int bh = swz >> 5, qt = swz & 31;
    const int b = bh >> 4, h = bh & 15;

    // hoist Q fragments (16 q-rows per wave), rows = b*2048 + qt*64 + w*16 + (l&15)
    const size_t rowQ = (size_t)(b * 2048 + qt * 64 + w * 16 + (l & 15));
    f16x8 qf[4];
#pragma unroll
    for (int kk = 0; kk < 4; ++kk)
        qf[kk] = *(const f16x8*)(Qg + rowQ * 2048 + h * 128 + kk * 32 + (l >> 4) * 8);

    f32x4 o[8];
#pragma unroll
    for (int i = 0; i < 8; ++i) o[i] = (f32x4){0.f, 0.f, 0.f, 0.f};
    float m[4] = {-3.0e38f, -3.0e38f, -3.0e38f, -3.0e38f};
    float s_l[4] = {0.f, 0.f, 0.f, 0.f};

    const f16* Kbase = Kg + (size_t)(b * 2048) * 2048 + h * 128;
    const f16* Vbase = Vt + (size_t)(b * 2048 + h * 128) * 2048;

    for (int st = 0; st < 2048; st += 64) {
        __syncthreads();
        // stage K tile [64][128]
#pragma unroll
        for (int i = 0; i < 4; ++i) {
            const int row = i * 16 + (tid >> 4);
            const int lg = (tid & 15) ^ (row & 15);
            gl2lds16(Kbase + (size_t)(st + row) * 2048 + lg * 8, Kl + row * 128 + (tid & 15) * 8);
        }
        // stage Vt tile [128][64]
#pragma unroll
        for (int i = 0; i < 4; ++i) {
            const int d = i * 32 + (tid >> 3);
            const int lg = (tid & 7) ^ (d & 7);
            gl2lds16(Vbase + (size_t)d * 2048 + st + lg * 8, Vl + d * 64 + (tid & 7) * 8);
        }
        __syncthreads();

        // QK^T: D[q][s], 4 col-tiles
        f32x4 sc[4];
#pragma unroll
        for (int n = 0; n < 4; ++n) sc[n] = (f32x4){0.f, 0.f, 0.f, 0.f};
#pragma unroll
        for (int kk = 0; kk < 4; ++kk) {
            const int g = kk * 4 + (l >> 4);
#pragma unroll
            for (int n = 0; n < 4; ++n) {
                const int srw = n * 16 + (l & 15);
                const f16x8 kf = *(const f16x8*)(Kl + srw * 128 + (g ^ (srw & 15)) * 8);
                sc[n] = MFMA16(qf[kk], kf, sc[n]);
            }
        }
#pragma unroll
        for (int n = 0; n < 4; ++n) sc[n] *= SCALE_F;

        // online softmax: row q = (l>>4)*4 + j, reduce over 16 lanes (l&15)
#pragma unroll
        for (int j = 0; j < 4; ++j) {
            float v0 = fmaxf(fmaxf(sc[0][j], sc[1][j]), fmaxf(sc[2][j], sc[3][j]));
            v0 = fmaxf(v0, __shfl_xor(v0, 1));
            v0 = fmaxf(v0, __shfl_xor(v0, 2));
            v0 = fmaxf(v0, __shfl_xor(v0, 4));
            v0 = fmaxf(v0, __shfl_xor(v0, 8));
            const float mn = fmaxf(m[j], v0);
            const float cr = __expf(m[j] - mn);
            m[j] = mn;
            const int q = ((l >> 4) << 2) + j;
            float sum = 0.f;
#pragma unroll
            for (int n = 0; n < 4; ++n) {
                const float p = __expf(sc[n][j] - mn);
                sum += p;
                const int s_loc = n * 16 + (l & 15);
                const int phys = (s_loc >> 3) ^ (q & 7);
                Pl[w][q * 64 + phys * 8 + (s_loc & 7)] = (f16)p;
            }
            sum += __shfl_xor(sum, 1);
            sum += __shfl_xor(sum, 2);
            sum += __shfl_xor(sum, 4);
            sum += __shfl_xor(sum, 8);
            s_l[j] = s_l[j] * cr + sum;
#pragma unroll
            for (int nd = 0; nd < 8; ++nd) o[nd][j] *= cr;
        }

        // PV: O[q][d] += P[q][s] @ V[s][d]  (V from Vt rows)
#pragma unroll
        for (int kk = 0; kk < 2; ++kk) {
            const int q = l & 15;
            const int g = kk * 4 + (l >> 4);
            const f16x8 pa = *(const f16x8*)(Pl[w] + q * 64 + (g ^ (q & 7)) * 8);
#pragma unroll
            for (int nd = 0; nd < 8; ++nd) {
                const int d = nd * 16 + (l & 15);
                const f16x8 vf = *(const f16x8*)(Vl + d * 64 + (g ^ (d & 7)) * 8);
                o[nd] = MFMA16(pa, vf, o[nd]);
            }
        }
    }

    // epilogue: normalize, write ctx f16 at [b*2048 + t][h*128 + d]
#pragma unroll
    for (int j = 0; j < 4; ++j) {
        const float inv = 1.0f / s_l[j];
        const size_t rowO = (size_t)(b * 2048 + qt * 64 + w * 16 + ((l >> 4) << 2) + j);
#pragma unroll
        for (int nd = 0; nd < 8; ++nd)
            Og[rowO * 2048 + h * 128 + nd * 16 + (l & 15)] = (f16)(o[nd][j] * inv);
    }
}

extern "C" void kernel_launch(void* const* d_in, const int* in_sizes, int n_in,
                              void* d_out, int out_size, void* d_ws, size_t ws_size,
                              hipStream_t stream) {
    const float* hs = (const float*)d_in[0];
    const float* es = (const float*)d_in[1];
    const float* Wq = (const float*)d_in[2];
    const float* Wk = (const float*)d_in[3];
    const float* Wv = (const float*)d_in[4];
    const float* Wo = (const float*)d_in[5];
    const float* cq = (const float*)d_in[6];
    const float* sq = (const float*)d_in[7];
    const float* ck = (const float*)d_in[8];
    const float* sk = (const float*)d_in[9];
    float* out = (float*)d_out;

    f16* hs16 = (f16*)d_ws;              // 8388608
    f16* es16 = hs16 + 8388608;          // 8388608
    f16* Wq16 = es16 + 8388608;          // 4194304 x4
    f16* Wk16 = Wq16 + 4194304;
    f16* Wv16 = Wk16 + 4194304;
    f16* Wo16 = Wv16 + 4194304;
    f16* Q16  = Wo16 + 4194304;          // 8388608
    f16* K16  = Q16 + 8388608;           // 8388608
    f16* Vt16 = K16 + 8388608;           // 8388608
    f16* ctx16 = hs16;                   // reuse (hs16 dead after Q-GEMM)

    const dim3 tB(256);
    cvt_f32_f16<<<dim3(4096), tB, 0, stream>>>(hs, hs16, 1048576);
    cvt_f32_f16<<<dim3(4096), tB, 0, stream>>>(es, es16, 1048576);
    cvt_f32_f16<<<dim3(2048), tB, 0, stream>>>(Wq, Wq16, 524288);
    cvt_f32_f16<<<dim3(2048), tB, 0, stream>>>(Wk, Wk16, 524288);
    cvt_f32_f16<<<dim3(2048), tB, 0, stream>>>(Wv, Wv16, 524288);
    cvt_f32_f16<<<dim3(2048), tB, 0, stream>>>(Wo, Wo16, 524288);

    gemm16<0><<<dim3(512), tB, 0, stream>>>(hs16, Wq16, Q16, 4096, 2048, 2048);
    gemm16<0><<<dim3(512), tB, 0, stream>>>(es16, Wk16, K16, 4096, 2048, 2048);
    gemm16<1><<<dim3(512), tB, 0, stream>>>(es16, Wv16, Vt16, 4096, 2048, 2048);

    rope16<<<dim3(4096), tB, 0, stream>>>(Q16, cq, sq);
    rope16<<<dim3(4096), tB, 0, stream>>>(K16, ck, sk);

    attn16<<<dim3(1024), tB, 0, stream>>>(Q16, K16, Vt16, ctx16);

    gemm16<2><<<dim3(512), tB, 0, stream>>>(ctx16, Wo16, out, 4096, 2048, 2048);
}

// Round 3
// 325.081 us; speedup vs baseline: 9.4635x; 1.1045x over previous
//
#include <hip/hip_runtime.h>
#include <cmath>

#define SCALE_F 0.088388347648318447f  // 1/sqrt(128)

typedef _Float16 f16;
typedef _Float16 f16x8 __attribute__((ext_vector_type(8)));
typedef float f32x4 __attribute__((ext_vector_type(4)));

#define MFMA16(a, b, c) __builtin_amdgcn_mfma_f32_16x16x32_f16(a, b, c, 0, 0, 0)

__device__ __forceinline__ void gl2lds16(const f16* g, f16* l) {
    __builtin_amdgcn_global_load_lds(
        (const __attribute__((address_space(1))) unsigned int*)g,
        (__attribute__((address_space(3))) unsigned int*)l, 16, 0, 0);
}

// ---------------- merged f32 -> f16 convert for all 6 inputs ----------------
// ws layout (f16): hs(8388608) es(8388608) Wq Wk Wv Wo (4194304 each), contiguous.
__global__ __launch_bounds__(256) void cvt_all(
    const float* __restrict__ hs, const float* __restrict__ es,
    const float* __restrict__ Wq, const float* __restrict__ Wk,
    const float* __restrict__ Wv, const float* __restrict__ Wo,
    f16* __restrict__ dst)
{
    const int c = blockIdx.x * 256 + threadIdx.x;   // chunk of 8 f32, 4194304 total
    const float* src; int off;
    if (c < 2097152) { src = (c < 1048576) ? hs : es; off = c & 1048575; }
    else {
        const int cc = c - 2097152;
        const int wsel = cc >> 19; off = cc & 524287;
        src = wsel == 0 ? Wq : wsel == 1 ? Wk : wsel == 2 ? Wv : Wo;
    }
    const float4* p = (const float4*)src + (size_t)off * 2;
    const float4 a = p[0], b2 = p[1];
    f16x8 o = {(f16)a.x, (f16)a.y, (f16)a.z, (f16)a.w,
               (f16)b2.x, (f16)b2.y, (f16)b2.z, (f16)b2.w};
    *(f16x8*)(dst + (size_t)c * 8) = o;
}

// ---------------- GEMM: C[M,N] = A[M,K] @ W[N,K]^T, fp16 in, MFMA ----------------
// OUT_MODE: 0 = f16 [M][N]
//           2 = f32 [M][N]
//           3 = f16 "Vt" write: out[((c>>11)*2048 + r)*2048 + (c&2047)]  (A=Wv, W=es)
//           4 = f16 [M][N] with fused RoPE (pairs along c; tables Cs/Sn [2048][64])
template <int OUT_MODE>
__global__ __launch_bounds__(256, 2) void gemm16(
    const f16* __restrict__ A, const f16* __restrict__ W,
    void* __restrict__ Cv, int M, int N, int K,
    const float* __restrict__ Cs, const float* __restrict__ Sn)
{
    __shared__ __align__(16) f16 Al[128 * 64];
    __shared__ __align__(16) f16 Bl[128 * 64];
    const int tid = threadIdx.x;
    const int l = tid & 63, w = tid >> 6;
    const int wr = w >> 1, wc = w & 1;

    // XCD-bijective swizzle (gridDim.x % 8 == 0)
    const int nwg = gridDim.x, cpx = nwg >> 3;
    const int bid = blockIdx.x;
    const int swz = (bid & 7) * cpx + (bid >> 3);
    const int nbn = N >> 7;
    const int bm = (swz / nbn) * 128, bn = (swz % nbn) * 128;

    f32x4 acc[4][4];
#pragma unroll
    for (int i = 0; i < 4; ++i)
#pragma unroll
        for (int j = 0; j < 4; ++j) acc[i][j] = (f32x4){0.f, 0.f, 0.f, 0.f};

    const int srow = tid >> 3;          // 0..31 (staging row base)
    const int sg = tid & 7;             // phys granule 0..7

    for (int k0 = 0; k0 < K; k0 += 64) {
        __syncthreads();
#pragma unroll
        for (int i = 0; i < 4; ++i) {
            const int row = i * 32 + srow;
            const int lg = sg ^ (row & 7);
            gl2lds16(A + (size_t)(bm + row) * K + k0 + lg * 8, Al + row * 64 + sg * 8);
            gl2lds16(W + (size_t)(bn + row) * K + k0 + lg * 8, Bl + row * 64 + sg * 8);
        }
        __syncthreads();
#pragma unroll
        for (int kk = 0; kk < 2; ++kk) {
            f16x8 a[4], b[4];
            const int g = kk * 4 + (l >> 4);
#pragma unroll
            for (int m = 0; m < 4; ++m) {
                const int row = wr * 64 + m * 16 + (l & 15);
                a[m] = *(const f16x8*)(Al + row * 64 + (g ^ (row & 7)) * 8);
            }
#pragma unroll
            for (int n = 0; n < 4; ++n) {
                const int row = wc * 64 + n * 16 + (l & 15);
                b[n] = *(const f16x8*)(Bl + row * 64 + (g ^ (row & 7)) * 8);
            }
#pragma unroll
            for (int m = 0; m < 4; ++m)
#pragma unroll
                for (int n = 0; n < 4; ++n)
                    acc[m][n] = MFMA16(a[m], b[n], acc[m][n]);
        }
    }

#pragma unroll
    for (int m = 0; m < 4; ++m)
#pragma unroll
        for (int n = 0; n < 4; ++n)
#pragma unroll
            for (int j = 0; j < 4; ++j) {
                const int r = bm + wr * 64 + m * 16 + ((l >> 4) << 2) + j;
                const int c = bn + wc * 64 + n * 16 + (l & 15);
                if (OUT_MODE == 0) {
                    ((f16*)Cv)[(size_t)r * N + c] = (f16)acc[m][n][j];
                } else if (OUT_MODE == 2) {
                    ((float*)Cv)[(size_t)r * N + c] = acc[m][n][j];
                } else if (OUT_MODE == 3) {
                    ((f16*)Cv)[(size_t)((c >> 11) * 2048 + r) * 2048 + (c & 2047)] = (f16)acc[m][n][j];
                } else if (OUT_MODE == 4) {
                    const float v = acc[m][n][j];
                    const float vp = __shfl_xor(v, 1);
                    const int t = r & 2047;
                    const int i2 = (c & 127) >> 1;
                    const float co = Cs[t * 64 + i2];
                    const float si = Sn[t * 64 + i2];
                    // even c: y = x0*co - x1*si (x0=v, x1=vp); odd c: y = x1*co + x0*si (x1=v, x0=vp)
                    const float y = (c & 1) ? fmaf(v, co, vp * si) : fmaf(v, co, -vp * si);
                    ((f16*)Cv)[(size_t)r * N + c] = (f16)y;
                }
            }
}

// ---------------- Flash attention fp16 MFMA: 8 waves x 16 q-rows, SB=64, dbuf 2-phase ----------------
__global__ __launch_bounds__(512, 4) void attn16(
    const f16* __restrict__ Qg, const f16* __restrict__ Kg,
    const f16* __restrict__ Vt, f16* __restrict__ Og)
{
    __shared__ __align__(16) f16 Kl[2][64 * 128];   // [s][d], swz ^(s&15)
    __shared__ __align__(16) f16 Vl[2][128 * 64];   // [d][s], swz ^(d&7)
    __shared__ __align__(16) f16 Pl[8][16 * 64];    // per-wave [q][s], swz ^(q&7)

    const int tid = threadIdx.x;
    const int l = tid & 63, w = tid >> 6;

    // XCD swizzle over 512 blocks: one head's q-tiles stay on one XCD
    const int bid = blockIdx.x;
    const int swz = (bid & 7) * 64 + (bid >> 3);
    const int bh = swz >> 4, qt = swz & 15;
    const int b = bh >> 4, h = bh & 15;

    // hoist Q fragments (16 q-rows per wave)
    const size_t rowQ = (size_t)(b * 2048 + qt * 128 + w * 16 + (l & 15));
    f16x8 qf[4];
#pragma unroll
    for (int kk = 0; kk < 4; ++kk)
        qf[kk] = *(const f16x8*)(Qg + rowQ * 2048 + h * 128 + kk * 32 + (l >> 4) * 8);

    f32x4 o[8];
#pragma unroll
    for (int i = 0; i < 8; ++i) o[i] = (f32x4){0.f, 0.f, 0.f, 0.f};
    float m[4] = {-3.0e38f, -3.0e38f, -3.0e38f, -3.0e38f};
    float s_l[4] = {0.f, 0.f, 0.f, 0.f};

    const f16* Kbase = Kg + (size_t)(b * 2048) * 2048 + h * 128;
    const f16* Vbase = Vt + (size_t)(b * 2048 + h * 128) * 2048;

#define STAGE(buf, st) do {                                                              \
    _Pragma("unroll")                                                                    \
    for (int u = 0; u < 2; ++u) {                                                        \
        const int idx = u * 512 + tid; const int row = idx >> 4, g = idx & 15;           \
        gl2lds16(Kbase + (size_t)((st) + row) * 2048 + (g ^ (row & 15)) * 8,             \
                 &Kl[buf][row * 128 + g * 8]);                                           \
    }                                                                                    \
    _Pragma("unroll")                                                                    \
    for (int u = 0; u < 2; ++u) {                                                        \
        const int idx = u * 512 + tid; const int d = idx >> 3, g = idx & 7;              \
        gl2lds16(Vbase + (size_t)d * 2048 + (st) + (g ^ (d & 7)) * 8,                    \
                 &Vl[buf][d * 64 + g * 8]);                                              \
    }                                                                                    \
} while (0)

    STAGE(0, 0);
    __syncthreads();

    int cur = 0;
    for (int t = 0; t < 32; ++t) {
        if (t < 31) STAGE(cur ^ 1, (t + 1) * 64);   // issue-early: overlaps compute below
        const f16* Kc = Kl[cur];
        const f16* Vc = Vl[cur];
        f16* Pw = Pl[w];

        // QK^T: D[q][s], 4 col-tiles
        f32x4 sc[4];
#pragma unroll
        for (int n = 0; n < 4; ++n) sc[n] = (f32x4){0.f, 0.f, 0.f, 0.f};
#pragma unroll
        for (int kk = 0; kk < 4; ++kk) {
            const int g = kk * 4 + (l >> 4);
#pragma unroll
            for (int n = 0; n < 4; ++n) {
                const int srw = n * 16 + (l & 15);
                const f16x8 kf = *(const f16x8*)(Kc + srw * 128 + (g ^ (srw & 15)) * 8);
                sc[n] = MFMA16(qf[kk], kf, sc[n]);
            }
        }
#pragma unroll
        for (int n = 0; n < 4; ++n) sc[n] *= SCALE_F;

        // online softmax with defer-max (T13, THR=8)
#pragma unroll
        for (int j = 0; j < 4; ++j) {
            float v0 = fmaxf(fmaxf(sc[0][j], sc[1][j]), fmaxf(sc[2][j], sc[3][j]));
            v0 = fmaxf(v0, __shfl_xor(v0, 1));
            v0 = fmaxf(v0, __shfl_xor(v0, 2));
            v0 = fmaxf(v0, __shfl_xor(v0, 4));
            v0 = fmaxf(v0, __shfl_xor(v0, 8));
            if (!__all(v0 <= m[j] + 8.0f)) {
                const float mn = fmaxf(m[j], v0);
                const float cr = __expf(m[j] - mn);
                m[j] = mn;
                s_l[j] *= cr;
#pragma unroll
                for (int nd = 0; nd < 8; ++nd) o[nd][j] *= cr;
            }
            const int q = ((l >> 4) << 2) + j;
            float sum = 0.f;
#pragma unroll
            for (int n = 0; n < 4; ++n) {
                const float p = __expf(sc[n][j] - m[j]);
                sum += p;
                const int s_loc = n * 16 + (l & 15);
                const int phys = (s_loc >> 3) ^ (q & 7);
                Pw[q * 64 + phys * 8 + (s_loc & 7)] = (f16)p;
            }
            sum += __shfl_xor(sum, 1);
            sum += __shfl_xor(sum, 2);
            sum += __shfl_xor(sum, 4);
            sum += __shfl_xor(sum, 8);
            s_l[j] += sum;
        }

        // PV: O[q][d] += P[q][s] @ V[s][d]
#pragma unroll
        for (int kk = 0; kk < 2; ++kk) {
            const int q = l & 15;
            const int g = kk * 4 + (l >> 4);
            const f16x8 pa = *(const f16x8*)(Pw + q * 64 + (g ^ (q & 7)) * 8);
#pragma unroll
            for (int nd = 0; nd < 8; ++nd) {
                const int d = nd * 16 + (l & 15);
                const f16x8 vf = *(const f16x8*)(Vc + d * 64 + (g ^ (d & 7)) * 8);
                o[nd] = MFMA16(pa, vf, o[nd]);
            }
        }
        __syncthreads();   // drains this wave's gl2lds (vmcnt) + all waves done with cur
        cur ^= 1;
    }
#undef STAGE

    // epilogue: normalize, write ctx f16 at [b*2048 + t][h*128 + d]
#pragma unroll
    for (int j = 0; j < 4; ++j) {
        const float inv = 1.0f / s_l[j];
        const size_t rowO = (size_t)(b * 2048 + qt * 128 + w * 16 + ((l >> 4) << 2) + j);
#pragma unroll
        for (int nd = 0; nd < 8; ++nd)
            Og[rowO * 2048 + h * 128 + nd * 16 + (l & 15)] = (f16)(o[nd][j] * inv);
    }
}

extern "C" void kernel_launch(void* const* d_in, const int* in_sizes, int n_in,
                              void* d_out, int out_size, void* d_ws, size_t ws_size,
                              hipStream_t stream) {
    const float* hs = (const float*)d_in[0];
    const float* es = (const float*)d_in[1];
    const float* Wq = (const float*)d_in[2];
    const float* Wk = (const float*)d_in[3];
    const float* Wv = (const float*)d_in[4];
    const float* Wo = (const float*)d_in[5];
    const float* cq = (const float*)d_in[6];
    const float* sq = (const float*)d_in[7];
    const float* ck = (const float*)d_in[8];
    const float* sk = (const float*)d_in[9];
    float* out = (float*)d_out;

    f16* hs16 = (f16*)d_ws;              // 8388608
    f16* es16 = hs16 + 8388608;          // 8388608
    f16* Wq16 = es16 + 8388608;          // 4194304 x4
    f16* Wk16 = Wq16 + 4194304;
    f16* Wv16 = Wk16 + 4194304;
    f16* Wo16 = Wv16 + 4194304;
    f16* Q16  = Wo16 + 4194304;          // 8388608
    f16* K16  = Q16 + 8388608;           // 8388608
    f16* Vt16 = K16 + 8388608;           // 8388608
    f16* ctx16 = hs16;                   // reuse (hs16 dead after Q-GEMM)

    const dim3 tB(256);
    cvt_all<<<dim3(16384), tB, 0, stream>>>(hs, es, Wq, Wk, Wv, Wo, hs16);

    // Q,K with fused RoPE; V computed transposed (A=Wv, B=es)
    gemm16<4><<<dim3(512), tB, 0, stream>>>(hs16, Wq16, Q16, 4096, 2048, 2048, cq, sq);
    gemm16<4><<<dim3(512), tB, 0, stream>>>(es16, Wk16, K16, 4096, 2048, 2048, ck, sk);
    gemm16<3><<<dim3(512), tB, 0, stream>>>(Wv16, es16, Vt16, 2048, 4096, 2048, nullptr, nullptr);

    attn16<<<dim3(512), dim3(512), 0, stream>>>(Q16, K16, Vt16, ctx16);

    gemm16<2><<<dim3(512), tB, 0, stream>>>(ctx16, Wo16, out, 4096, 2048, 2048, nullptr, nullptr);
}

// Round 7
// 303.879 us; speedup vs baseline: 10.1237x; 1.0698x over previous
//
#include <hip/hip_runtime.h>
#include <cmath>

#define SCALE_F 0.088388347648318447f  // 1/sqrt(128)

typedef _Float16 f16;
typedef _Float16 f16x8 __attribute__((ext_vector_type(8)));
typedef _Float16 f16x4 __attribute__((ext_vector_type(4)));
typedef float f32x4 __attribute__((ext_vector_type(4)));
typedef float f32x16 __attribute__((ext_vector_type(16)));
typedef unsigned int u32;
typedef unsigned int u32x4 __attribute__((ext_vector_type(4)));

#define MFMA16(a, b, c) __builtin_amdgcn_mfma_f32_16x16x32_f16(a, b, c, 0, 0, 0)
#define MFMA32(a, b, c) __builtin_amdgcn_mfma_f32_32x32x16_f16(a, b, c, 0, 0, 0)
#define Z16 ((f32x16){0.f,0.f,0.f,0.f,0.f,0.f,0.f,0.f,0.f,0.f,0.f,0.f,0.f,0.f,0.f,0.f})

__device__ __forceinline__ void gl2lds16(const f16* g, f16* l) {
    __builtin_amdgcn_global_load_lds(
        (const __attribute__((address_space(1))) unsigned int*)g,
        (__attribute__((address_space(3))) unsigned int*)l, 16, 0, 0);
}

// RNE pack of two f32 into one u32 of 2xf16 (element0 = x, element1 = y)
__device__ __forceinline__ u32 pk2(float x, float y) {
    const unsigned short a = __builtin_bit_cast(unsigned short, (f16)x);
    const unsigned short b = __builtin_bit_cast(unsigned short, (f16)y);
    return (u32)a | ((u32)b << 16);
}
// own + partner(lane^32) / max(own, partner): duplicate via explicit fresh register
// (=&v) so the two swap operands can never be coalesced; result is symmetric in the
// two halves, so it is correct under EITHER permlane32_swap direction semantics.
__device__ __forceinline__ float fswapsum(float x) {
    u32 a = __builtin_bit_cast(u32, x), b;
    asm volatile("v_mov_b32 %0, %1" : "=&v"(b) : "v"(a));
    asm volatile("v_permlane32_swap_b32 %0, %1" : "+v"(a), "+v"(b));
    return __builtin_bit_cast(float, a) + __builtin_bit_cast(float, b);
}
__device__ __forceinline__ float fswapmax(float x) {
    u32 a = __builtin_bit_cast(u32, x), b;
    asm volatile("v_mov_b32 %0, %1" : "=&v"(b) : "v"(a));
    asm volatile("v_permlane32_swap_b32 %0, %1" : "+v"(a), "+v"(b));
    return fmaxf(__builtin_bit_cast(float, a), __builtin_bit_cast(float, b));
}

// ---------------- merged f32 -> f16 convert for all 6 inputs ----------------
__global__ __launch_bounds__(256) void cvt_all(
    const float* __restrict__ hs, const float* __restrict__ es,
    const float* __restrict__ Wq, const float* __restrict__ Wk,
    const float* __restrict__ Wv, const float* __restrict__ Wo,
    f16* __restrict__ dst)
{
    const int c = blockIdx.x * 256 + threadIdx.x;   // chunk of 8 f32, 4194304 total
    const float* src; int off;
    if (c < 2097152) { src = (c < 1048576) ? hs : es; off = c & 1048575; }
    else {
        const int cc = c - 2097152;
        const int wsel = cc >> 19; off = cc & 524287;
        src = wsel == 0 ? Wq : wsel == 1 ? Wk : wsel == 2 ? Wv : Wo;
    }
    const float4* p = (const float4*)src + (size_t)off * 2;
    const float4 a = p[0], b2 = p[1];
    f16x8 o = {(f16)a.x, (f16)a.y, (f16)a.z, (f16)a.w,
               (f16)b2.x, (f16)b2.y, (f16)b2.z, (f16)b2.w};
    *(f16x8*)(dst + (size_t)c * 8) = o;
}

// ---------------- GEMM: C[M,N] = A[M,K] @ W[N,K]^T, fp16 in, MFMA ----------------
// OUT_MODE: 0 = f16 [M][N]
//           2 = f32 [M][N]
//           3 = f16 "Vt" write: out[((c>>11)*2048 + r)*2048 + (c&2047)]  (A=Wv, W=es)
//           4 = f16 [M][N] with fused RoPE (pairs along c; tables Cs/Sn [2048][64])
template <int OUT_MODE>
__global__ __launch_bounds__(256, 2) void gemm16(
    const f16* __restrict__ A, const f16* __restrict__ W,
    void* __restrict__ Cv, int M, int N, int K,
    const float* __restrict__ Cs, const float* __restrict__ Sn)
{
    __shared__ __align__(16) f16 Al[128 * 64];
    __shared__ __align__(16) f16 Bl[128 * 64];
    const int tid = threadIdx.x;
    const int l = tid & 63, w = tid >> 6;
    const int wr = w >> 1, wc = w & 1;

    const int nwg = gridDim.x, cpx = nwg >> 3;
    const int bid = blockIdx.x;
    const int swz = (bid & 7) * cpx + (bid >> 3);
    const int nbn = N >> 7;
    const int bm = (swz / nbn) * 128, bn = (swz % nbn) * 128;

    f32x4 acc[4][4];
#pragma unroll
    for (int i = 0; i < 4; ++i)
#pragma unroll
        for (int j = 0; j < 4; ++j) acc[i][j] = (f32x4){0.f, 0.f, 0.f, 0.f};

    const int srow = tid >> 3;
    const int sg = tid & 7;

    for (int k0 = 0; k0 < K; k0 += 64) {
        __syncthreads();
#pragma unroll
        for (int i = 0; i < 4; ++i) {
            const int row = i * 32 + srow;
            const int lg = sg ^ (row & 7);
            gl2lds16(A + (size_t)(bm + row) * K + k0 + lg * 8, Al + row * 64 + sg * 8);
            gl2lds16(W + (size_t)(bn + row) * K + k0 + lg * 8, Bl + row * 64 + sg * 8);
        }
        __syncthreads();
#pragma unroll
        for (int kk = 0; kk < 2; ++kk) {
            f16x8 a[4], b[4];
            const int g = kk * 4 + (l >> 4);
#pragma unroll
            for (int m = 0; m < 4; ++m) {
                const int row = wr * 64 + m * 16 + (l & 15);
                a[m] = *(const f16x8*)(Al + row * 64 + (g ^ (row & 7)) * 8);
            }
#pragma unroll
            for (int n = 0; n < 4; ++n) {
                const int row = wc * 64 + n * 16 + (l & 15);
                b[n] = *(const f16x8*)(Bl + row * 64 + (g ^ (row & 7)) * 8);
            }
#pragma unroll
            for (int m = 0; m < 4; ++m)
#pragma unroll
                for (int n = 0; n < 4; ++n)
                    acc[m][n] = MFMA16(a[m], b[n], acc[m][n]);
        }
    }

#pragma unroll
    for (int m = 0; m < 4; ++m)
#pragma unroll
        for (int n = 0; n < 4; ++n)
#pragma unroll
            for (int j = 0; j < 4; ++j) {
                const int r = bm + wr * 64 + m * 16 + ((l >> 4) << 2) + j;
                const int c = bn + wc * 64 + n * 16 + (l & 15);
                if (OUT_MODE == 0) {
                    ((f16*)Cv)[(size_t)r * N + c] = (f16)acc[m][n][j];
                } else if (OUT_MODE == 2) {
                    ((float*)Cv)[(size_t)r * N + c] = acc[m][n][j];
                } else if (OUT_MODE == 3) {
                    ((f16*)Cv)[(size_t)((c >> 11) * 2048 + r) * 2048 + (c & 2047)] = (f16)acc[m][n][j];
                } else if (OUT_MODE == 4) {
                    const float v = acc[m][n][j];
                    const float vp = __shfl_xor(v, 1);
                    const int t = r & 2047;
                    const int i2 = (c & 127) >> 1;
                    const float co = Cs[t * 64 + i2];
                    const float si = Sn[t * 64 + i2];
                    const float y = (c & 1) ? fmaf(v, co, vp * si) : fmaf(v, co, -vp * si);
                    ((f16*)Cv)[(size_t)r * N + c] = (f16)y;
                }
            }
}

// ---------------- Flash attention: 8 waves x 32 q-rows, 32x32x16 MFMA, swapped QK^T ----------------
// P stays in registers. The PV k-slot mapping is chosen so each lane's A-frag uses ONLY
// its own P-values (no cross-lane exchange): slot(hi, e) -> s = hi*4 + (e&3) + (e>>2)*8.
// V-frags are gathered with the SAME mapping via two b64 LDS reads (mapping-invariance:
// any bijection works as long as A and B agree). exp2-domain softmax, defer-max THR=8.
__global__ __launch_bounds__(512, 1) void attn16(
    const f16* __restrict__ Qg, const f16* __restrict__ Kg,
    const f16* __restrict__ Vt, f16* __restrict__ Og)
{
    __shared__ __align__(16) f16 Kl[2][64 * 128];   // [s][d], granule swz ^(s&15)
    __shared__ __align__(16) f16 Vl[2][128 * 64];   // [d][s], granule swz ^(d&7)
    __shared__ float bnc[8][32];                    // per-wave q-indexed broadcast

    const int tid = threadIdx.x;
    const int l = tid & 63, w = tid >> 6;
    const int l31 = l & 31, hi = l >> 5;
    const int hi4 = hi * 4;

    // XCD swizzle: 256 blocks, 4 heads' worth of q-tiles per XCD
    const int bid = blockIdx.x;
    const int swz = (bid & 7) * 32 + (bid >> 3);
    const int bh = swz >> 3, qt = swz & 7;
    const int b = bh >> 4, h = bh & 15;

    // Q fragments (B-operand): lane's q = l31; k = kc*16 + hi*8 + e. Scale folded (log2e).
    const int qrow = b * 2048 + qt * 256 + w * 32 + l31;
    const f16 qsc = (f16)(0.088388347648318447f * 1.44269504088896f);
    f16x8 qf[8];
#pragma unroll
    for (int kc = 0; kc < 8; ++kc) {
        f16x8 t0 = *(const f16x8*)(Qg + (size_t)qrow * 2048 + h * 128 + kc * 16 + hi * 8);
#pragma unroll
        for (int e = 0; e < 8; ++e) t0[e] = t0[e] * qsc;
        qf[kc] = t0;
    }

    f32x16 o[4] = {Z16, Z16, Z16, Z16};   // O[q=crow(r,hi)][d=dt*32+l31]
    float mrow = -3.0e38f, lrow = 0.0f;   // per-lane, q = l31 (dup across hi)

    const f16* Kbase = Kg + (size_t)(b * 2048) * 2048 + h * 128;
    const f16* Vbase = Vt + (size_t)(b * 2048 + h * 128) * 2048;

#define STAGE(buf, st) do {                                                              \
    _Pragma("unroll")                                                                    \
    for (int u = 0; u < 2; ++u) {                                                        \
        const int idx = u * 512 + tid; const int row = idx >> 4, g = idx & 15;           \
        gl2lds16(Kbase + (size_t)((st) + row) * 2048 + (g ^ (row & 15)) * 8,             \
                 &Kl[buf][row * 128 + g * 8]);                                           \
    }                                                                                    \
    _Pragma("unroll")                                                                    \
    for (int u = 0; u < 2; ++u) {                                                        \
        const int idx = u * 512 + tid; const int d = idx >> 3, g = idx & 7;              \
        gl2lds16(Vbase + (size_t)d * 2048 + (st) + (g ^ (d & 7)) * 8,                    \
                 &Vl[buf][d * 64 + g * 8]);                                              \
    }                                                                                    \
} while (0)

    STAGE(0, 0);
    __syncthreads();

    int cur = 0;
    for (int t = 0; t < 32; ++t) {
        if (t < 31) STAGE(cur ^ 1, (t + 1) * 64);
        const f16* Kc = Kl[cur];
        const f16* Vc = Vl[cur];

        // ---- QK^T (swapped): P^T[s][q], lane holds q=l31, s = (r&3)+8*(r>>2)+4*hi (+32 for p1)
        f32x16 p0 = Z16, p1 = Z16;
        __builtin_amdgcn_s_setprio(1);
#pragma unroll
        for (int kc = 0; kc < 8; ++kc) {
            const int g = ((kc * 2 + hi) ^ (l31 & 15)) * 8;
            const f16x8 k0 = *(const f16x8*)(Kc + l31 * 128 + g);
            const f16x8 k1 = *(const f16x8*)(Kc + (32 + l31) * 128 + g);
            p0 = MFMA32(k0, qf[kc], p0);
            p1 = MFMA32(k1, qf[kc], p1);
        }
        __builtin_amdgcn_s_setprio(0);

        // ---- online softmax (log2 domain), full row per lane-pair
        float mx = fmaxf(p0[0], p1[0]);
#pragma unroll
        for (int r = 1; r < 16; ++r) mx = fmaxf(mx, fmaxf(p0[r], p1[r]));
        mx = fswapmax(mx);

        if (!__all(mx <= mrow + 8.0f)) {
            const float mn = fmaxf(mrow, mx);
            const float cr = exp2f(mrow - mn);
            mrow = mn;
            lrow *= cr;
            if (hi == 0) bnc[w][l31] = cr;
#pragma unroll
            for (int r = 0; r < 16; ++r) {
                const float crr = bnc[w][(r & 3) + 8 * (r >> 2) + 4 * hi];
                o[0][r] *= crr; o[1][r] *= crr; o[2][r] *= crr; o[3][r] *= crr;
            }
        }

        float s0 = 0.f, s1 = 0.f, s2 = 0.f, s3 = 0.f;
#pragma unroll
        for (int r = 0; r < 16; r += 4) {
            p0[r]     = exp2f(p0[r]     - mrow); s0 += p0[r];
            p0[r + 1] = exp2f(p0[r + 1] - mrow); s1 += p0[r + 1];
            p0[r + 2] = exp2f(p0[r + 2] - mrow); s2 += p0[r + 2];
            p0[r + 3] = exp2f(p0[r + 3] - mrow); s3 += p0[r + 3];
        }
#pragma unroll
        for (int r = 0; r < 16; r += 4) {
            p1[r]     = exp2f(p1[r]     - mrow); s0 += p1[r];
            p1[r + 1] = exp2f(p1[r + 1] - mrow); s1 += p1[r + 1];
            p1[r + 2] = exp2f(p1[r + 2] - mrow); s2 += p1[r + 2];
            p1[r + 3] = exp2f(p1[r + 3] - mrow); s3 += p1[r + 3];
        }
        lrow += fswapsum((s0 + s1) + (s2 + s3));

        // ---- pack P -> A-frags from OWN lane values only (no cross-lane ops)
        // pf[ks] slot e holds P[q][s = ks*16 + hi*4 + (e&3) + (e>>2)*8]
        f16x8 pf[4];
#pragma unroll
        for (int ksl = 0; ksl < 2; ++ksl) {
            u32x4 w0 = {pk2(p0[8*ksl+0], p0[8*ksl+1]), pk2(p0[8*ksl+2], p0[8*ksl+3]),
                        pk2(p0[8*ksl+4], p0[8*ksl+5]), pk2(p0[8*ksl+6], p0[8*ksl+7])};
            pf[ksl] = __builtin_bit_cast(f16x8, w0);
            u32x4 w1 = {pk2(p1[8*ksl+0], p1[8*ksl+1]), pk2(p1[8*ksl+2], p1[8*ksl+3]),
                        pk2(p1[8*ksl+4], p1[8*ksl+5]), pk2(p1[8*ksl+6], p1[8*ksl+7])};
            pf[2 + ksl] = __builtin_bit_cast(f16x8, w1);
        }

        // ---- PV: O[q][d] += P[q][s] @ V[s][d]; V-frag gathered with the SAME slot map
        __builtin_amdgcn_s_setprio(1);
#pragma unroll
        for (int dt = 0; dt < 4; ++dt) {
            const f16* vrow = Vc + (dt * 32 + l31) * 64;
#pragma unroll
            for (int ks = 0; ks < 4; ++ks) {
                const f16x4 vlo = *(const f16x4*)(vrow + ((ks * 2)     ^ (l31 & 7)) * 8 + hi4);
                const f16x4 vhi = *(const f16x4*)(vrow + ((ks * 2 + 1) ^ (l31 & 7)) * 8 + hi4);
                const f16x8 vf = __builtin_shufflevector(vlo, vhi, 0, 1, 2, 3, 4, 5, 6, 7);
                o[dt] = MFMA32(pf[ks], vf, o[dt]);
            }
        }
        __builtin_amdgcn_s_setprio(0);

        __syncthreads();
        cur ^= 1;
    }
#undef STAGE

    // ---- epilogue: normalize (1/l broadcast by q-row), write ctx [b*2048+t][h*128+d]
    const float inv = 1.0f / lrow;
    if (hi == 0) bnc[w][l31] = inv;
#pragma unroll
    for (int r = 0; r < 16; ++r) {
        const int qq = (r & 3) + 8 * (r >> 2) + 4 * hi;
        const float ir = bnc[w][qq];
        const size_t row = (size_t)(b * 2048 + qt * 256 + w * 32 + qq);
#pragma unroll
        for (int dt = 0; dt < 4; ++dt)
            Og[row * 2048 + h * 128 + dt * 32 + l31] = (f16)(o[dt][r] * ir);
    }
}

extern "C" void kernel_launch(void* const* d_in, const int* in_sizes, int n_in,
                              void* d_out, int out_size, void* d_ws, size_t ws_size,
                              hipStream_t stream) {
    const float* hs = (const float*)d_in[0];
    const float* es = (const float*)d_in[1];
    const float* Wq = (const float*)d_in[2];
    const float* Wk = (const float*)d_in[3];
    const float* Wv = (const float*)d_in[4];
    const float* Wo = (const float*)d_in[5];
    const float* cq = (const float*)d_in[6];
    const float* sq = (const float*)d_in[7];
    const float* ck = (const float*)d_in[8];
    const float* sk = (const float*)d_in[9];
    float* out = (float*)d_out;

    f16* hs16 = (f16*)d_ws;
    f16* es16 = hs16 + 8388608;
    f16* Wq16 = es16 + 8388608;
    f16* Wk16 = Wq16 + 4194304;
    f16* Wv16 = Wk16 + 4194304;
    f16* Wo16 = Wv16 + 4194304;
    f16* Q16  = Wo16 + 4194304;
    f16* K16  = Q16 + 8388608;
    f16* Vt16 = K16 + 8388608;
    f16* ctx16 = hs16;   // reuse (hs16 dead after Q-GEMM)

    const dim3 tB(256);
    cvt_all<<<dim3(16384), tB, 0, stream>>>(hs, es, Wq, Wk, Wv, Wo, hs16);

    gemm16<4><<<dim3(512), tB, 0, stream>>>(hs16, Wq16, Q16, 4096, 2048, 2048, cq, sq);
    gemm16<4><<<dim3(512), tB, 0, stream>>>(es16, Wk16, K16, 4096, 2048, 2048, ck, sk);
    gemm16<3><<<dim3(512), tB, 0, stream>>>(Wv16, es16, Vt16, 2048, 4096, 2048, nullptr, nullptr);

    attn16<<<dim3(256), dim3(512), 0, stream>>>(Q16, K16, Vt16, ctx16);

    gemm16<2><<<dim3(512), tB, 0, stream>>>(ctx16, Wo16, out, 4096, 2048, 2048, nullptr, nullptr);
}

// Round 8
// 292.556 us; speedup vs baseline: 10.5156x; 1.0387x over previous
//
#include <hip/hip_runtime.h>
#include <cmath>

#define SCALE_F 0.088388347648318447f  // 1/sqrt(128)

typedef _Float16 f16;
typedef _Float16 f16x8 __attribute__((ext_vector_type(8)));
typedef _Float16 f16x4 __attribute__((ext_vector_type(4)));
typedef float f32x4 __attribute__((ext_vector_type(4)));
typedef float f32x16 __attribute__((ext_vector_type(16)));
typedef unsigned int u32;
typedef unsigned int u32x4 __attribute__((ext_vector_type(4)));

#define MFMA16(a, b, c) __builtin_amdgcn_mfma_f32_16x16x32_f16(a, b, c, 0, 0, 0)
#define MFMA32(a, b, c) __builtin_amdgcn_mfma_f32_32x32x16_f16(a, b, c, 0, 0, 0)
#define Z16 ((f32x16){0.f,0.f,0.f,0.f,0.f,0.f,0.f,0.f,0.f,0.f,0.f,0.f,0.f,0.f,0.f,0.f})
#define EX2(x) __builtin_amdgcn_exp2f(x)

__device__ __forceinline__ void gl2lds16(const f16* g, f16* l) {
    __builtin_amdgcn_global_load_lds(
        (const __attribute__((address_space(1))) unsigned int*)g,
        (__attribute__((address_space(3))) unsigned int*)l, 16, 0, 0);
}

// RNE pack of two f32 into one u32 of 2xf16 (element0 = x, element1 = y)
__device__ __forceinline__ u32 pk2(float x, float y) {
    const unsigned short a = __builtin_bit_cast(unsigned short, (f16)x);
    const unsigned short b = __builtin_bit_cast(unsigned short, (f16)y);
    return (u32)a | ((u32)b << 16);
}
// own + partner(lane^32) / max(own, partner): duplicate via explicit fresh register
// (=&v) so the two swap operands can never be coalesced; result is symmetric in the
// two halves, so it is correct under EITHER permlane32_swap direction semantics.
__device__ __forceinline__ float fswapsum(float x) {
    u32 a = __builtin_bit_cast(u32, x), b;
    asm volatile("v_mov_b32 %0, %1" : "=&v"(b) : "v"(a));
    asm volatile("v_permlane32_swap_b32 %0, %1" : "+v"(a), "+v"(b));
    return __builtin_bit_cast(float, a) + __builtin_bit_cast(float, b);
}
__device__ __forceinline__ float fswapmax(float x) {
    u32 a = __builtin_bit_cast(u32, x), b;
    asm volatile("v_mov_b32 %0, %1" : "=&v"(b) : "v"(a));
    asm volatile("v_permlane32_swap_b32 %0, %1" : "+v"(a), "+v"(b));
    return fmaxf(__builtin_bit_cast(float, a), __builtin_bit_cast(float, b));
}

// ---------------- merged f32 -> f16 convert for all 6 inputs ----------------
__global__ __launch_bounds__(256) void cvt_all(
    const float* __restrict__ hs, const float* __restrict__ es,
    const float* __restrict__ Wq, const float* __restrict__ Wk,
    const float* __restrict__ Wv, const float* __restrict__ Wo,
    f16* __restrict__ dst)
{
    const int c = blockIdx.x * 256 + threadIdx.x;   // chunk of 8 f32, 4194304 total
    const float* src; int off;
    if (c < 2097152) { src = (c < 1048576) ? hs : es; off = c & 1048575; }
    else {
        const int cc = c - 2097152;
        const int wsel = cc >> 19; off = cc & 524287;
        src = wsel == 0 ? Wq : wsel == 1 ? Wk : wsel == 2 ? Wv : Wo;
    }
    const float4* p = (const float4*)src + (size_t)off * 2;
    const float4 a = p[0], b2 = p[1];
    f16x8 o = {(f16)a.x, (f16)a.y, (f16)a.z, (f16)a.w,
               (f16)b2.x, (f16)b2.y, (f16)b2.z, (f16)b2.w};
    *(f16x8*)(dst + (size_t)c * 8) = o;
}

// ---------------- GEMM: C[M,N] = A[M,K] @ W[N,K]^T, fp16 in, MFMA ----------------
// OUT_MODE: 0 = f16 [M][N]
//           2 = f32 [M][N]
//           3 = f16 "Vt" write: out[((c>>11)*2048 + r)*2048 + (c&2047)]  (A=Wv, W=es)
//           4 = f16 [M][N] with fused RoPE (pairs along c; tables Cs/Sn [2048][64])
template <int OUT_MODE>
__global__ __launch_bounds__(256, 2) void gemm16(
    const f16* __restrict__ A, const f16* __restrict__ W,
    void* __restrict__ Cv, int M, int N, int K,
    const float* __restrict__ Cs, const float* __restrict__ Sn)
{
    __shared__ __align__(16) f16 Al[128 * 64];
    __shared__ __align__(16) f16 Bl[128 * 64];
    const int tid = threadIdx.x;
    const int l = tid & 63, w = tid >> 6;
    const int wr = w >> 1, wc = w & 1;

    const int nwg = gridDim.x, cpx = nwg >> 3;
    const int bid = blockIdx.x;
    const int swz = (bid & 7) * cpx + (bid >> 3);
    const int nbn = N >> 7;
    const int bm = (swz / nbn) * 128, bn = (swz % nbn) * 128;

    f32x4 acc[4][4];
#pragma unroll
    for (int i = 0; i < 4; ++i)
#pragma unroll
        for (int j = 0; j < 4; ++j) acc[i][j] = (f32x4){0.f, 0.f, 0.f, 0.f};

    const int srow = tid >> 3;
    const int sg = tid & 7;

    for (int k0 = 0; k0 < K; k0 += 64) {
        __syncthreads();
#pragma unroll
        for (int i = 0; i < 4; ++i) {
            const int row = i * 32 + srow;
            const int lg = sg ^ (row & 7);
            gl2lds16(A + (size_t)(bm + row) * K + k0 + lg * 8, Al + row * 64 + sg * 8);
            gl2lds16(W + (size_t)(bn + row) * K + k0 + lg * 8, Bl + row * 64 + sg * 8);
        }
        __syncthreads();
#pragma unroll
        for (int kk = 0; kk < 2; ++kk) {
            f16x8 a[4], b[4];
            const int g = kk * 4 + (l >> 4);
#pragma unroll
            for (int m = 0; m < 4; ++m) {
                const int row = wr * 64 + m * 16 + (l & 15);
                a[m] = *(const f16x8*)(Al + row * 64 + (g ^ (row & 7)) * 8);
            }
#pragma unroll
            for (int n = 0; n < 4; ++n) {
                const int row = wc * 64 + n * 16 + (l & 15);
                b[n] = *(const f16x8*)(Bl + row * 64 + (g ^ (row & 7)) * 8);
            }
#pragma unroll
            for (int m = 0; m < 4; ++m)
#pragma unroll
                for (int n = 0; n < 4; ++n)
                    acc[m][n] = MFMA16(a[m], b[n], acc[m][n]);
        }
    }

#pragma unroll
    for (int m = 0; m < 4; ++m)
#pragma unroll
        for (int n = 0; n < 4; ++n)
#pragma unroll
            for (int j = 0; j < 4; ++j) {
                const int r = bm + wr * 64 + m * 16 + ((l >> 4) << 2) + j;
                const int c = bn + wc * 64 + n * 16 + (l & 15);
                if (OUT_MODE == 0) {
                    ((f16*)Cv)[(size_t)r * N + c] = (f16)acc[m][n][j];
                } else if (OUT_MODE == 2) {
                    ((float*)Cv)[(size_t)r * N + c] = acc[m][n][j];
                } else if (OUT_MODE == 3) {
                    ((f16*)Cv)[(size_t)((c >> 11) * 2048 + r) * 2048 + (c & 2047)] = (f16)acc[m][n][j];
                } else if (OUT_MODE == 4) {
                    const float v = acc[m][n][j];
                    const float vp = __shfl_xor(v, 1);
                    const int t = r & 2047;
                    const int i2 = (c & 127) >> 1;
                    const float co = Cs[t * 64 + i2];
                    const float si = Sn[t * 64 + i2];
                    const float y = (c & 1) ? fmaf(v, co, vp * si) : fmaf(v, co, -vp * si);
                    ((f16*)Cv)[(size_t)r * N + c] = (f16)y;
                }
            }
}

// ---------------- Flash attention: 4 waves x 32 q-rows, 32x32x16 MFMA, swapped QK^T ----------------
// 512 blocks (2/CU). P stays in registers; PV k-slot map uses only own-lane P values.
// Fast exp2 (v_exp_f32), depth-5 max/sum trees, defer-max THR=8, exp2-domain softmax.
__global__ __launch_bounds__(256, 2) void attn16(
    const f16* __restrict__ Qg, const f16* __restrict__ Kg,
    const f16* __restrict__ Vt, f16* __restrict__ Og)
{
    __shared__ __align__(16) f16 Kl[2][64 * 128];   // [s][d], granule swz ^(s&15)
    __shared__ __align__(16) f16 Vl[2][128 * 64];   // [d][s], granule swz ^(d&7)
    __shared__ float bnc[4][32];                    // per-wave q-indexed broadcast

    const int tid = threadIdx.x;
    const int l = tid & 63, w = tid >> 6;           // w in 0..3
    const int l31 = l & 31, hi = l >> 5;
    const int hi4 = hi * 4;

    // XCD swizzle: 512 blocks, 64 consecutive per XCD
    const int bid = blockIdx.x;
    const int swz = (bid & 7) * 64 + (bid >> 3);
    const int bh = swz >> 4, qt = swz & 15;
    const int b = bh >> 4, h = bh & 15;

    // Q fragments (B-operand): lane's q = l31; k = kc*16 + hi*8 + e. Scale folded (log2e).
    const int qrow = b * 2048 + qt * 128 + w * 32 + l31;
    const f16 qsc = (f16)(0.088388347648318447f * 1.44269504088896f);
    f16x8 qf[8];
#pragma unroll
    for (int kc = 0; kc < 8; ++kc) {
        f16x8 t0 = *(const f16x8*)(Qg + (size_t)qrow * 2048 + h * 128 + kc * 16 + hi * 8);
#pragma unroll
        for (int e = 0; e < 8; ++e) t0[e] = t0[e] * qsc;
        qf[kc] = t0;
    }

    f32x16 o[4] = {Z16, Z16, Z16, Z16};   // O[q=crow(r,hi)][d=dt*32+l31]
    float mrow = -3.0e38f, lrow = 0.0f;   // per-lane, q = l31 (dup across hi)

    const f16* Kbase = Kg + (size_t)(b * 2048) * 2048 + h * 128;
    const f16* Vbase = Vt + (size_t)(b * 2048 + h * 128) * 2048;

#define STAGE(buf, st) do {                                                              \
    _Pragma("unroll")                                                                    \
    for (int u = 0; u < 4; ++u) {                                                        \
        const int idx = u * 256 + tid; const int row = idx >> 4, g = idx & 15;           \
        gl2lds16(Kbase + (size_t)((st) + row) * 2048 + (g ^ (row & 15)) * 8,             \
                 &Kl[buf][row * 128 + g * 8]);                                           \
    }                                                                                    \
    _Pragma("unroll")                                                                    \
    for (int u = 0; u < 4; ++u) {                                                        \
        const int idx = u * 256 + tid; const int d = idx >> 3, g = idx & 7;              \
        gl2lds16(Vbase + (size_t)d * 2048 + (st) + (g ^ (d & 7)) * 8,                    \
                 &Vl[buf][d * 64 + g * 8]);                                              \
    }                                                                                    \
} while (0)

    STAGE(0, 0);
    __syncthreads();

    int cur = 0;
    for (int t = 0; t < 32; ++t) {
        if (t < 31) STAGE(cur ^ 1, (t + 1) * 64);
        const f16* Kc = Kl[cur];
        const f16* Vc = Vl[cur];

        // ---- QK^T (swapped): P^T[s][q], lane holds q=l31, s = (r&3)+8*(r>>2)+4*hi (+32 for p1)
        f32x16 p0 = Z16, p1 = Z16;
        __builtin_amdgcn_s_setprio(1);
#pragma unroll
        for (int kc = 0; kc < 8; ++kc) {
            const int g = ((kc * 2 + hi) ^ (l31 & 15)) * 8;
            const f16x8 k0 = *(const f16x8*)(Kc + l31 * 128 + g);
            const f16x8 k1 = *(const f16x8*)(Kc + (32 + l31) * 128 + g);
            p0 = MFMA32(k0, qf[kc], p0);
            p1 = MFMA32(k1, qf[kc], p1);
        }
        __builtin_amdgcn_s_setprio(0);

        // ---- online softmax (log2 domain): depth-5 max tree, then lane-pair combine
        float mt[16];
#pragma unroll
        for (int r = 0; r < 16; ++r) mt[r] = fmaxf(p0[r], p1[r]);
#pragma unroll
        for (int r = 0; r < 8; ++r) mt[r] = fmaxf(mt[r], mt[r + 8]);
#pragma unroll
        for (int r = 0; r < 4; ++r) mt[r] = fmaxf(mt[r], mt[r + 4]);
        float mx = fmaxf(fmaxf(mt[0], mt[1]), fmaxf(mt[2], mt[3]));
        mx = fswapmax(mx);

        if (!__all(mx <= mrow + 8.0f)) {
            const float mn = fmaxf(mrow, mx);
            const float cr = EX2(mrow - mn);
            mrow = mn;
            lrow *= cr;
            if (hi == 0) bnc[w][l31] = cr;
#pragma unroll
            for (int r = 0; r < 16; ++r) {
                const float crr = bnc[w][(r & 3) + 8 * (r >> 2) + 4 * hi];
                o[0][r] *= crr; o[1][r] *= crr; o[2][r] *= crr; o[3][r] *= crr;
            }
        }

        // exp2 (1 v_exp_f32 each) + depth-5 sum tree
        float st16[16];
#pragma unroll
        for (int r = 0; r < 16; ++r) {
            p0[r] = EX2(p0[r] - mrow);
            p1[r] = EX2(p1[r] - mrow);
            st16[r] = p0[r] + p1[r];
        }
#pragma unroll
        for (int r = 0; r < 8; ++r) st16[r] += st16[r + 8];
#pragma unroll
        for (int r = 0; r < 4; ++r) st16[r] += st16[r + 4];
        lrow += fswapsum((st16[0] + st16[1]) + (st16[2] + st16[3]));

        // ---- pack P -> A-frags from OWN lane values only (no cross-lane ops)
        // pf[ks] slot e holds P[q][s = ks*16 + hi*4 + (e&3) + (e>>2)*8]
        f16x8 pf[4];
#pragma unroll
        for (int ksl = 0; ksl < 2; ++ksl) {
            u32x4 w0 = {pk2(p0[8*ksl+0], p0[8*ksl+1]), pk2(p0[8*ksl+2], p0[8*ksl+3]),
                        pk2(p0[8*ksl+4], p0[8*ksl+5]), pk2(p0[8*ksl+6], p0[8*ksl+7])};
            pf[ksl] = __builtin_bit_cast(f16x8, w0);
            u32x4 w1 = {pk2(p1[8*ksl+0], p1[8*ksl+1]), pk2(p1[8*ksl+2], p1[8*ksl+3]),
                        pk2(p1[8*ksl+4], p1[8*ksl+5]), pk2(p1[8*ksl+6], p1[8*ksl+7])};
            pf[2 + ksl] = __builtin_bit_cast(f16x8, w1);
        }

        // ---- PV: O[q][d] += P[q][s] @ V[s][d]; V-frag gathered with the SAME slot map
        __builtin_amdgcn_s_setprio(1);
#pragma unroll
        for (int dt = 0; dt < 4; ++dt) {
            const f16* vrow = Vc + (dt * 32 + l31) * 64;
#pragma unroll
            for (int ks = 0; ks < 4; ++ks) {
                const f16x4 vlo = *(const f16x4*)(vrow + ((ks * 2)     ^ (l31 & 7)) * 8 + hi4);
                const f16x4 vhi = *(const f16x4*)(vrow + ((ks * 2 + 1) ^ (l31 & 7)) * 8 + hi4);
                const f16x8 vf = __builtin_shufflevector(vlo, vhi, 0, 1, 2, 3, 4, 5, 6, 7);
                o[dt] = MFMA32(pf[ks], vf, o[dt]);
            }
        }
        __builtin_amdgcn_s_setprio(0);

        __syncthreads();
        cur ^= 1;
    }
#undef STAGE

    // ---- epilogue: normalize (1/l broadcast by q-row), write ctx [b*2048+t][h*128+d]
    const float inv = 1.0f / lrow;
    if (hi == 0) bnc[w][l31] = inv;
#pragma unroll
    for (int r = 0; r < 16; ++r) {
        const int qq = (r & 3) + 8 * (r >> 2) + 4 * hi;
        const float ir = bnc[w][qq];
        const size_t row = (size_t)(b * 2048 + qt * 128 + w * 32 + qq);
#pragma unroll
        for (int dt = 0; dt < 4; ++dt)
            Og[row * 2048 + h * 128 + dt * 32 + l31] = (f16)(o[dt][r] * ir);
    }
}

extern "C" void kernel_launch(void* const* d_in, const int* in_sizes, int n_in,
                              void* d_out, int out_size, void* d_ws, size_t ws_size,
                              hipStream_t stream) {
    const float* hs = (const float*)d_in[0];
    const float* es = (const float*)d_in[1];
    const float* Wq = (const float*)d_in[2];
    const float* Wk = (const float*)d_in[3];
    const float* Wv = (const float*)d_in[4];
    const float* Wo = (const float*)d_in[5];
    const float* cq = (const float*)d_in[6];
    const float* sq = (const float*)d_in[7];
    const float* ck = (const float*)d_in[8];
    const float* sk = (const float*)d_in[9];
    float* out = (float*)d_out;

    f16* hs16 = (f16*)d_ws;
    f16* es16 = hs16 + 8388608;
    f16* Wq16 = es16 + 8388608;
    f16* Wk16 = Wq16 + 4194304;
    f16* Wv16 = Wk16 + 4194304;
    f16* Wo16 = Wv16 + 4194304;
    f16* Q16  = Wo16 + 4194304;
    f16* K16  = Q16 + 8388608;
    f16* Vt16 = K16 + 8388608;
    f16* ctx16 = hs16;   // reuse (hs16 dead after Q-GEMM)

    const dim3 tB(256);
    cvt_all<<<dim3(16384), tB, 0, stream>>>(hs, es, Wq, Wk, Wv, Wo, hs16);

    gemm16<4><<<dim3(512), tB, 0, stream>>>(hs16, Wq16, Q16, 4096, 2048, 2048, cq, sq);
    gemm16<4><<<dim3(512), tB, 0, stream>>>(es16, Wk16, K16, 4096, 2048, 2048, ck, sk);
    gemm16<3><<<dim3(512), tB, 0, stream>>>(Wv16, es16, Vt16, 2048, 4096, 2048, nullptr, nullptr);

    attn16<<<dim3(512), tB, 0, stream>>>(Q16, K16, Vt16, ctx16);

    gemm16<2><<<dim3(512), tB, 0, stream>>>(ctx16, Wo16, out, 4096, 2048, 2048, nullptr, nullptr);
}

// Round 9
// 292.177 us; speedup vs baseline: 10.5292x; 1.0013x over previous
//
#include <hip/hip_runtime.h>
#include <cmath>

#define SCALE_F 0.088388347648318447f  // 1/sqrt(128)

typedef _Float16 f16;
typedef _Float16 f16x8 __attribute__((ext_vector_type(8)));
typedef _Float16 f16x4 __attribute__((ext_vector_type(4)));
typedef float f32x4 __attribute__((ext_vector_type(4)));
typedef float f32x16 __attribute__((ext_vector_type(16)));
typedef unsigned int u32;
typedef unsigned int u32x4 __attribute__((ext_vector_type(4)));

#define MFMA16(a, b, c) __builtin_amdgcn_mfma_f32_16x16x32_f16(a, b, c, 0, 0, 0)
#define MFMA32(a, b, c) __builtin_amdgcn_mfma_f32_32x32x16_f16(a, b, c, 0, 0, 0)
#define Z16 ((f32x16){0.f,0.f,0.f,0.f,0.f,0.f,0.f,0.f,0.f,0.f,0.f,0.f,0.f,0.f,0.f,0.f})
#define EX2(x) __builtin_amdgcn_exp2f(x)

__device__ __forceinline__ void gl2lds16(const f16* g, f16* l) {
    __builtin_amdgcn_global_load_lds(
        (const __attribute__((address_space(1))) unsigned int*)g,
        (__attribute__((address_space(3))) unsigned int*)l, 16, 0, 0);
}

// RNE pack of two f32 into one u32 of 2xf16 (element0 = x, element1 = y)
__device__ __forceinline__ u32 pk2(float x, float y) {
    const unsigned short a = __builtin_bit_cast(unsigned short, (f16)x);
    const unsigned short b = __builtin_bit_cast(unsigned short, (f16)y);
    return (u32)a | ((u32)b << 16);
}
// own + partner(lane^32): explicit fresh register (=&v) so operands can't coalesce;
// symmetric combine -> correct under either permlane32_swap direction.
__device__ __forceinline__ float fswapsum(float x) {
    u32 a = __builtin_bit_cast(u32, x), b;
    asm volatile("v_mov_b32 %0, %1" : "=&v"(b) : "v"(a));
    asm volatile("v_permlane32_swap_b32 %0, %1" : "+v"(a), "+v"(b));
    return __builtin_bit_cast(float, a) + __builtin_bit_cast(float, b);
}
__device__ __forceinline__ float fswapmax(float x) {
    u32 a = __builtin_bit_cast(u32, x), b;
    asm volatile("v_mov_b32 %0, %1" : "=&v"(b) : "v"(a));
    asm volatile("v_permlane32_swap_b32 %0, %1" : "+v"(a), "+v"(b));
    return fmaxf(__builtin_bit_cast(float, a), __builtin_bit_cast(float, b));
}

// ---------------- merged f32 -> f16 convert for all 6 inputs ----------------
__global__ __launch_bounds__(256) void cvt_all(
    const float* __restrict__ hs, const float* __restrict__ es,
    const float* __restrict__ Wq, const float* __restrict__ Wk,
    const float* __restrict__ Wv, const float* __restrict__ Wo,
    f16* __restrict__ dst)
{
    const int c = blockIdx.x * 256 + threadIdx.x;   // chunk of 8 f32, 4194304 total
    const float* src; int off;
    if (c < 2097152) { src = (c < 1048576) ? hs : es; off = c & 1048575; }
    else {
        const int cc = c - 2097152;
        const int wsel = cc >> 19; off = cc & 524287;
        src = wsel == 0 ? Wq : wsel == 1 ? Wk : wsel == 2 ? Wv : Wo;
    }
    const float4* p = (const float4*)src + (size_t)off * 2;
    const float4 a = p[0], b2 = p[1];
    f16x8 o = {(f16)a.x, (f16)a.y, (f16)a.z, (f16)a.w,
               (f16)b2.x, (f16)b2.y, (f16)b2.z, (f16)b2.w};
    *(f16x8*)(dst + (size_t)c * 8) = o;
}

// ---------------- GEMM: C[M,N] = A[M,K] @ W[N,K]^T, fp16 in, MFMA ----------------
// OUT_MODE: 0 = f16 [M][N]
//           2 = f32 [M][N]
//           3 = f16 "Vt" write: out[((c>>11)*2048 + r)*2048 + (c&2047)]  (A=Wv, W=es)
//           4 = f16 [M][N] with fused RoPE (pairs along c; tables Cs/Sn [2048][64])
template <int OUT_MODE>
__global__ __launch_bounds__(256, 2) void gemm16(
    const f16* __restrict__ A, const f16* __restrict__ W,
    void* __restrict__ Cv, int M, int N, int K,
    const float* __restrict__ Cs, const float* __restrict__ Sn)
{
    __shared__ __align__(16) f16 Al[128 * 64];
    __shared__ __align__(16) f16 Bl[128 * 64];
    const int tid = threadIdx.x;
    const int l = tid & 63, w = tid >> 6;
    const int wr = w >> 1, wc = w & 1;

    const int nwg = gridDim.x, cpx = nwg >> 3;
    const int bid = blockIdx.x;
    const int swz = (bid & 7) * cpx + (bid >> 3);
    const int nbn = N >> 7;
    const int bm = (swz / nbn) * 128, bn = (swz % nbn) * 128;

    f32x4 acc[4][4];
#pragma unroll
    for (int i = 0; i < 4; ++i)
#pragma unroll
        for (int j = 0; j < 4; ++j) acc[i][j] = (f32x4){0.f, 0.f, 0.f, 0.f};

    const int srow = tid >> 3;
    const int sg = tid & 7;

    for (int k0 = 0; k0 < K; k0 += 64) {
        __syncthreads();
#pragma unroll
        for (int i = 0; i < 4; ++i) {
            const int row = i * 32 + srow;
            const int lg = sg ^ (row & 7);
            gl2lds16(A + (size_t)(bm + row) * K + k0 + lg * 8, Al + row * 64 + sg * 8);
            gl2lds16(W + (size_t)(bn + row) * K + k0 + lg * 8, Bl + row * 64 + sg * 8);
        }
        __syncthreads();
#pragma unroll
        for (int kk = 0; kk < 2; ++kk) {
            f16x8 a[4], b[4];
            const int g = kk * 4 + (l >> 4);
#pragma unroll
            for (int m = 0; m < 4; ++m) {
                const int row = wr * 64 + m * 16 + (l & 15);
                a[m] = *(const f16x8*)(Al + row * 64 + (g ^ (row & 7)) * 8);
            }
#pragma unroll
            for (int n = 0; n < 4; ++n) {
                const int row = wc * 64 + n * 16 + (l & 15);
                b[n] = *(const f16x8*)(Bl + row * 64 + (g ^ (row & 7)) * 8);
            }
#pragma unroll
            for (int m = 0; m < 4; ++m)
#pragma unroll
                for (int n = 0; n < 4; ++n)
                    acc[m][n] = MFMA16(a[m], b[n], acc[m][n]);
        }
    }

#pragma unroll
    for (int m = 0; m < 4; ++m)
#pragma unroll
        for (int n = 0; n < 4; ++n)
#pragma unroll
            for (int j = 0; j < 4; ++j) {
                const int r = bm + wr * 64 + m * 16 + ((l >> 4) << 2) + j;
                const int c = bn + wc * 64 + n * 16 + (l & 15);
                if (OUT_MODE == 0) {
                    ((f16*)Cv)[(size_t)r * N + c] = (f16)acc[m][n][j];
                } else if (OUT_MODE == 2) {
                    ((float*)Cv)[(size_t)r * N + c] = acc[m][n][j];
                } else if (OUT_MODE == 3) {
                    ((f16*)Cv)[(size_t)((c >> 11) * 2048 + r) * 2048 + (c & 2047)] = (f16)acc[m][n][j];
                } else if (OUT_MODE == 4) {
                    const float v = acc[m][n][j];
                    const float vp = __shfl_xor(v, 1);
                    const int t = r & 2047;
                    const int i2 = (c & 127) >> 1;
                    const float co = Cs[t * 64 + i2];
                    const float si = Sn[t * 64 + i2];
                    const float y = (c & 1) ? fmaf(v, co, vp * si) : fmaf(v, co, -vp * si);
                    ((f16*)Cv)[(size_t)r * N + c] = (f16)y;
                }
            }
}

// ---------------- Flash attention: 4 waves x 32 q-rows, 32x32x16 MFMA, swapped QK^T ----------------
// V LDS tile reinterpreted as 64 rows x 256B (two d-rows per LDS row): 16-granule XOR
// swizzle ^(d2&15) makes the b64 PV gather 2-way (free) instead of 4-way.
__global__ __launch_bounds__(256, 2) void attn16(
    const f16* __restrict__ Qg, const f16* __restrict__ Kg,
    const f16* __restrict__ Vt, f16* __restrict__ Og)
{
    __shared__ __align__(16) f16 Kl[2][64 * 128];   // [s][d], granule swz ^(s&15)
    __shared__ __align__(16) f16 Vl[2][64 * 128];   // [d2][2 d-rows interleaved], swz ^(d2&15)
    __shared__ float bnc[4][32];                    // per-wave q-indexed broadcast

    const int tid = threadIdx.x;
    const int l = tid & 63, w = tid >> 6;           // w in 0..3
    const int l31 = l & 31, hi = l >> 5;
    const int hi4 = hi * 4;
    const int u16 = l31 >> 1;                       // V-read XOR key (4 bits)
    const int dodd = l31 & 1;

    // XCD swizzle: 512 blocks, 64 consecutive per XCD
    const int bid = blockIdx.x;
    const int swz = (bid & 7) * 64 + (bid >> 3);
    const int bh = swz >> 4, qt = swz & 15;
    const int b = bh >> 4, h = bh & 15;

    // Q fragments (B-operand): lane's q = l31; k = kc*16 + hi*8 + e. Scale folded (log2e).
    const int qrow = b * 2048 + qt * 128 + w * 32 + l31;
    const f16 qsc = (f16)(0.088388347648318447f * 1.44269504088896f);
    f16x8 qf[8];
#pragma unroll
    for (int kc = 0; kc < 8; ++kc) {
        f16x8 t0 = *(const f16x8*)(Qg + (size_t)qrow * 2048 + h * 128 + kc * 16 + hi * 8);
#pragma unroll
        for (int e = 0; e < 8; ++e) t0[e] = t0[e] * qsc;
        qf[kc] = t0;
    }

    f32x16 o[4] = {Z16, Z16, Z16, Z16};   // O[q=crow(r,hi)][d=dt*32+l31]
    float mrow = -3.0e38f, lrow = 0.0f;   // per-lane, q = l31 (dup across hi)

    const f16* Kbase = Kg + (size_t)(b * 2048) * 2048 + h * 128;
    const f16* Vbase = Vt + (size_t)(b * 2048 + h * 128) * 2048;

#define STAGE(buf, st) do {                                                              \
    _Pragma("unroll")                                                                    \
    for (int u = 0; u < 4; ++u) {                                                        \
        const int idx = u * 256 + tid; const int row = idx >> 4, g = idx & 15;           \
        gl2lds16(Kbase + (size_t)((st) + row) * 2048 + (g ^ (row & 15)) * 8,             \
                 &Kl[buf][row * 128 + g * 8]);                                           \
    }                                                                                    \
    _Pragma("unroll")                                                                    \
    for (int u = 0; u < 4; ++u) {                                                        \
        const int idx = u * 256 + tid; const int d2 = idx >> 4, g = idx & 15;            \
        const int lg = g ^ (d2 & 15);                                                    \
        gl2lds16(Vbase + (size_t)(d2 * 2 + (lg >> 3)) * 2048 + (st) + (lg & 7) * 8,      \
                 &Vl[buf][d2 * 128 + g * 8]);                                            \
    }                                                                                    \
} while (0)

    STAGE(0, 0);
    __syncthreads();

    int cur = 0;
    for (int t = 0; t < 32; ++t) {
        if (t < 31) STAGE(cur ^ 1, (t + 1) * 64);
        const f16* Kc = Kl[cur];
        const f16* Vc = Vl[cur];

        // ---- QK^T (swapped): P^T[s][q], lane holds q=l31, s = (r&3)+8*(r>>2)+4*hi (+32 for p1)
        f32x16 p0 = Z16, p1 = Z16;
        __builtin_amdgcn_s_setprio(1);
#pragma unroll
        for (int kc = 0; kc < 8; ++kc) {
            const int g = ((kc * 2 + hi) ^ (l31 & 15)) * 8;
            const f16x8 k0 = *(const f16x8*)(Kc + l31 * 128 + g);
            const f16x8 k1 = *(const f16x8*)(Kc + (32 + l31) * 128 + g);
            p0 = MFMA32(k0, qf[kc], p0);
            p1 = MFMA32(k1, qf[kc], p1);
        }
        __builtin_amdgcn_s_setprio(0);

        // ---- online softmax (log2 domain): depth-5 max tree, then lane-pair combine
        float mt[16];
#pragma unroll
        for (int r = 0; r < 16; ++r) mt[r] = fmaxf(p0[r], p1[r]);
#pragma unroll
        for (int r = 0; r < 8; ++r) mt[r] = fmaxf(mt[r], mt[r + 8]);
#pragma unroll
        for (int r = 0; r < 4; ++r) mt[r] = fmaxf(mt[r], mt[r + 4]);
        float mx = fmaxf(fmaxf(mt[0], mt[1]), fmaxf(mt[2], mt[3]));
        mx = fswapmax(mx);

        if (!__all(mx <= mrow + 8.0f)) {
            const float mn = fmaxf(mrow, mx);
            const float cr = EX2(mrow - mn);
            mrow = mn;
            lrow *= cr;
            if (hi == 0) bnc[w][l31] = cr;
#pragma unroll
            for (int r = 0; r < 16; ++r) {
                const float crr = bnc[w][(r & 3) + 8 * (r >> 2) + 4 * hi];
                o[0][r] *= crr; o[1][r] *= crr; o[2][r] *= crr; o[3][r] *= crr;
            }
        }

        // exp2 (1 v_exp_f32 each) + depth-5 sum tree
        float st16[16];
#pragma unroll
        for (int r = 0; r < 16; ++r) {
            p0[r] = EX2(p0[r] - mrow);
            p1[r] = EX2(p1[r] - mrow);
            st16[r] = p0[r] + p1[r];
        }
#pragma unroll
        for (int r = 0; r < 8; ++r) st16[r] += st16[r + 8];
#pragma unroll
        for (int r = 0; r < 4; ++r) st16[r] += st16[r + 4];
        lrow += fswapsum((st16[0] + st16[1]) + (st16[2] + st16[3]));

        // ---- pack P -> A-frags from OWN lane values only (no cross-lane ops)
        // pf[ks] slot e holds P[q][s = ks*16 + hi*4 + (e&3) + (e>>2)*8]
        f16x8 pf[4];
#pragma unroll
        for (int ksl = 0; ksl < 2; ++ksl) {
            u32x4 w0 = {pk2(p0[8*ksl+0], p0[8*ksl+1]), pk2(p0[8*ksl+2], p0[8*ksl+3]),
                        pk2(p0[8*ksl+4], p0[8*ksl+5]), pk2(p0[8*ksl+6], p0[8*ksl+7])};
            pf[ksl] = __builtin_bit_cast(f16x8, w0);
            u32x4 w1 = {pk2(p1[8*ksl+0], p1[8*ksl+1]), pk2(p1[8*ksl+2], p1[8*ksl+3]),
                        pk2(p1[8*ksl+4], p1[8*ksl+5]), pk2(p1[8*ksl+6], p1[8*ksl+7])};
            pf[2 + ksl] = __builtin_bit_cast(f16x8, w1);
        }

        // ---- PV: O[q][d] += P[q][s] @ V[s][d]; lane's d-col = dt*32+l31 lives in
        // LDS row d2 = dt*16 + (l31>>1), half dodd. 16-slot XOR -> 2-way free.
        __builtin_amdgcn_s_setprio(1);
#pragma unroll
        for (int dt = 0; dt < 4; ++dt) {
            const f16* vrow = Vc + (dt * 16 + u16) * 128;
#pragma unroll
            for (int ks = 0; ks < 4; ++ks) {
                const f16x4 vlo = *(const f16x4*)(vrow + ((dodd * 8 + ks * 2)     ^ u16) * 8 + hi4);
                const f16x4 vhi = *(const f16x4*)(vrow + ((dodd * 8 + ks * 2 + 1) ^ u16) * 8 + hi4);
                const f16x8 vf = __builtin_shufflevector(vlo, vhi, 0, 1, 2, 3, 4, 5, 6, 7);
                o[dt] = MFMA32(pf[ks], vf, o[dt]);
            }
        }
        __builtin_amdgcn_s_setprio(0);

        __syncthreads();
        cur ^= 1;
    }
#undef STAGE

    // ---- epilogue: normalize (1/l broadcast by q-row), write ctx [b*2048+t][h*128+d]
    const float inv = 1.0f / lrow;
    if (hi == 0) bnc[w][l31] = inv;
#pragma unroll
    for (int r = 0; r < 16; ++r) {
        const int qq = (r & 3) + 8 * (r >> 2) + 4 * hi;
        const float ir = bnc[w][qq];
        const size_t row = (size_t)(b * 2048 + qt * 128 + w * 32 + qq);
#pragma unroll
        for (int dt = 0; dt < 4; ++dt)
            Og[row * 2048 + h * 128 + dt * 32 + l31] = (f16)(o[dt][r] * ir);
    }
}

extern "C" void kernel_launch(void* const* d_in, const int* in_sizes, int n_in,
                              void* d_out, int out_size, void* d_ws, size_t ws_size,
                              hipStream_t stream) {
    const float* hs = (const float*)d_in[0];
    const float* es = (const float*)d_in[1];
    const float* Wq = (const float*)d_in[2];
    const float* Wk = (const float*)d_in[3];
    const float* Wv = (const float*)d_in[4];
    const float* Wo = (const float*)d_in[5];
    const float* cq = (const float*)d_in[6];
    const float* sq = (const float*)d_in[7];
    const float* ck = (const float*)d_in[8];
    const float* sk = (const float*)d_in[9];
    float* out = (float*)d_out;

    f16* hs16 = (f16*)d_ws;
    f16* es16 = hs16 + 8388608;
    f16* Wq16 = es16 + 8388608;
    f16* Wk16 = Wq16 + 4194304;
    f16* Wv16 = Wk16 + 4194304;
    f16* Wo16 = Wv16 + 4194304;
    f16* Q16  = Wo16 + 4194304;
    f16* K16  = Q16 + 8388608;
    f16* Vt16 = K16 + 8388608;
    f16* ctx16 = hs16;   // reuse (hs16 dead after Q-GEMM)

    const dim3 tB(256);
    cvt_all<<<dim3(16384), tB, 0, stream>>>(hs, es, Wq, Wk, Wv, Wo, hs16);

    gemm16<4><<<dim3(512), tB, 0, stream>>>(hs16, Wq16, Q16, 4096, 2048, 2048, cq, sq);
    gemm16<4><<<dim3(512), tB, 0, stream>>>(es16, Wk16, K16, 4096, 2048, 2048, ck, sk);
    gemm16<3><<<dim3(512), tB, 0, stream>>>(Wv16, es16, Vt16, 2048, 4096, 2048, nullptr, nullptr);

    attn16<<<dim3(512), tB, 0, stream>>>(Q16, K16, Vt16, ctx16);

    gemm16<2><<<dim3(512), tB, 0, stream>>>(ctx16, Wo16, out, 4096, 2048, 2048, nullptr, nullptr);
}

// Round 10
// 290.105 us; speedup vs baseline: 10.6044x; 1.0071x over previous
//
#include <hip/hip_runtime.h>
#include <cmath>

#define SCALE_F 0.088388347648318447f  // 1/sqrt(128)

typedef _Float16 f16;
typedef _Float16 f16x8 __attribute__((ext_vector_type(8)));
typedef _Float16 f16x4 __attribute__((ext_vector_type(4)));
typedef float f32x4 __attribute__((ext_vector_type(4)));
typedef float f32x16 __attribute__((ext_vector_type(16)));
typedef unsigned int u32;
typedef unsigned int u32x2 __attribute__((ext_vector_type(2)));
typedef unsigned int u32x4 __attribute__((ext_vector_type(4)));

#define MFMA16(a, b, c) __builtin_amdgcn_mfma_f32_16x16x32_f16(a, b, c, 0, 0, 0)
#define MFMA32(a, b, c) __builtin_amdgcn_mfma_f32_32x32x16_f16(a, b, c, 0, 0, 0)
#define Z16 ((f32x16){0.f,0.f,0.f,0.f,0.f,0.f,0.f,0.f,0.f,0.f,0.f,0.f,0.f,0.f,0.f,0.f})
#define EX2(x) __builtin_amdgcn_exp2f(x)

__device__ __forceinline__ void gl2lds16(const f16* g, f16* l) {
    __builtin_amdgcn_global_load_lds(
        (const __attribute__((address_space(1))) unsigned int*)g,
        (__attribute__((address_space(3))) unsigned int*)l, 16, 0, 0);
}

// RNE pack of two f32 into one u32 of 2xf16 (element0 = x, element1 = y)
__device__ __forceinline__ u32 pk2(float x, float y) {
    const unsigned short a = __builtin_bit_cast(unsigned short, (f16)x);
    const unsigned short b = __builtin_bit_cast(unsigned short, (f16)y);
    return (u32)a | ((u32)b << 16);
}
// own + partner(lane^32): explicit fresh register (=&v) so operands can't coalesce;
// symmetric combine -> correct under either permlane32_swap direction.
__device__ __forceinline__ float fswapsum(float x) {
    u32 a = __builtin_bit_cast(u32, x), b;
    asm volatile("v_mov_b32 %0, %1" : "=&v"(b) : "v"(a));
    asm volatile("v_permlane32_swap_b32 %0, %1" : "+v"(a), "+v"(b));
    return __builtin_bit_cast(float, a) + __builtin_bit_cast(float, b);
}
__device__ __forceinline__ float fswapmax(float x) {
    u32 a = __builtin_bit_cast(u32, x), b;
    asm volatile("v_mov_b32 %0, %1" : "=&v"(b) : "v"(a));
    asm volatile("v_permlane32_swap_b32 %0, %1" : "+v"(a), "+v"(b));
    return fmaxf(__builtin_bit_cast(float, a), __builtin_bit_cast(float, b));
}

// ---------------- merged f32 -> f16 convert for all 6 inputs ----------------
__global__ __launch_bounds__(256) void cvt_all(
    const float* __restrict__ hs, const float* __restrict__ es,
    const float* __restrict__ Wq, const float* __restrict__ Wk,
    const float* __restrict__ Wv, const float* __restrict__ Wo,
    f16* __restrict__ dst)
{
    const int c = blockIdx.x * 256 + threadIdx.x;   // chunk of 8 f32, 4194304 total
    const float* src; int off;
    if (c < 2097152) { src = (c < 1048576) ? hs : es; off = c & 1048575; }
    else {
        const int cc = c - 2097152;
        const int wsel = cc >> 19; off = cc & 524287;
        src = wsel == 0 ? Wq : wsel == 1 ? Wk : wsel == 2 ? Wv : Wo;
    }
    const float4* p = (const float4*)src + (size_t)off * 2;
    const float4 a = p[0], b2 = p[1];
    f16x8 o = {(f16)a.x, (f16)a.y, (f16)a.z, (f16)a.w,
               (f16)b2.x, (f16)b2.y, (f16)b2.z, (f16)b2.w};
    *(f16x8*)(dst + (size_t)c * 8) = o;
}

// ---------------- GEMM: C[M,N] = A[M,K] @ W[N,K]^T, fp16 in, MFMA ----------------
// OUT_MODE: 0 = f16 [M][N]
//           2 = f32 [M][N]
//           3 = f16 "Vt" write: out[((c>>11)*2048 + r)*2048 + (c&2047)]  (A=Wv, W=es)
//           4 = f16 [M][N] with fused RoPE (pairs along c; tables Cs/Sn [2048][64])
template <int OUT_MODE>
__global__ __launch_bounds__(256, 2) void gemm16(
    const f16* __restrict__ A, const f16* __restrict__ W,
    void* __restrict__ Cv, int M, int N, int K,
    const float* __restrict__ Cs, const float* __restrict__ Sn)
{
    __shared__ __align__(16) f16 Al[128 * 64];
    __shared__ __align__(16) f16 Bl[128 * 64];
    const int tid = threadIdx.x;
    const int l = tid & 63, w = tid >> 6;
    const int wr = w >> 1, wc = w & 1;

    const int nwg = gridDim.x, cpx = nwg >> 3;
    const int bid = blockIdx.x;
    const int swz = (bid & 7) * cpx + (bid >> 3);
    const int nbn = N >> 7;
    const int bm = (swz / nbn) * 128, bn = (swz % nbn) * 128;

    f32x4 acc[4][4];
#pragma unroll
    for (int i = 0; i < 4; ++i)
#pragma unroll
        for (int j = 0; j < 4; ++j) acc[i][j] = (f32x4){0.f, 0.f, 0.f, 0.f};

    const int srow = tid >> 3;
    const int sg = tid & 7;

    for (int k0 = 0; k0 < K; k0 += 64) {
        __syncthreads();
#pragma unroll
        for (int i = 0; i < 4; ++i) {
            const int row = i * 32 + srow;
            const int lg = sg ^ (row & 7);
            gl2lds16(A + (size_t)(bm + row) * K + k0 + lg * 8, Al + row * 64 + sg * 8);
            gl2lds16(W + (size_t)(bn + row) * K + k0 + lg * 8, Bl + row * 64 + sg * 8);
        }
        __syncthreads();
#pragma unroll
        for (int kk = 0; kk < 2; ++kk) {
            f16x8 a[4], b[4];
            const int g = kk * 4 + (l >> 4);
#pragma unroll
            for (int m = 0; m < 4; ++m) {
                const int row = wr * 64 + m * 16 + (l & 15);
                a[m] = *(const f16x8*)(Al + row * 64 + (g ^ (row & 7)) * 8);
            }
#pragma unroll
            for (int n = 0; n < 4; ++n) {
                const int row = wc * 64 + n * 16 + (l & 15);
                b[n] = *(const f16x8*)(Bl + row * 64 + (g ^ (row & 7)) * 8);
            }
#pragma unroll
            for (int m = 0; m < 4; ++m)
#pragma unroll
                for (int n = 0; n < 4; ++n)
                    acc[m][n] = MFMA16(a[m], b[n], acc[m][n]);
        }
    }

#pragma unroll
    for (int m = 0; m < 4; ++m)
#pragma unroll
        for (int n = 0; n < 4; ++n)
#pragma unroll
            for (int j = 0; j < 4; ++j) {
                const int r = bm + wr * 64 + m * 16 + ((l >> 4) << 2) + j;
                const int c = bn + wc * 64 + n * 16 + (l & 15);
                if (OUT_MODE == 0) {
                    ((f16*)Cv)[(size_t)r * N + c] = (f16)acc[m][n][j];
                } else if (OUT_MODE == 2) {
                    ((float*)Cv)[(size_t)r * N + c] = acc[m][n][j];
                } else if (OUT_MODE == 3) {
                    ((f16*)Cv)[(size_t)((c >> 11) * 2048 + r) * 2048 + (c & 2047)] = (f16)acc[m][n][j];
                } else if (OUT_MODE == 4) {
                    const float v = acc[m][n][j];
                    const float vp = __shfl_xor(v, 1);
                    const int t = r & 2047;
                    const int i2 = (c & 127) >> 1;
                    const float co = Cs[t * 64 + i2];
                    const float si = Sn[t * 64 + i2];
                    const float y = (c & 1) ? fmaf(v, co, vp * si) : fmaf(v, co, -vp * si);
                    ((f16*)Cv)[(size_t)r * N + c] = (f16)y;
                }
            }
}

// ---------------- Flash attention: 4 waves x 32 q-rows, 32x32x16 MFMA, swapped QK^T ----------------
// Reg-staged K/V into PADDED LDS (K pitch 132 halfs, V pitch 68 halfs -> bank rotation 2
// words/row -> all ds_read_b64 are 2-way = conflict-free). T14 split: loads issued before
// QK^T, LDS writes after softmax. No XOR swizzles anywhere.
__global__ __launch_bounds__(256, 2) void attn16(
    const f16* __restrict__ Qg, const f16* __restrict__ Kg,
    const f16* __restrict__ Vt, f16* __restrict__ Og)
{
    __shared__ __align__(16) f16 Kl[2][64 * 132];   // [s][d], pitch 132 (264B, +2 words rot)
    __shared__ __align__(16) f16 Vl[2][128 * 68];   // [d][s], pitch 68  (136B, +2 words rot)
    __shared__ float bnc[4][32];                    // per-wave q-indexed broadcast

    const int tid = threadIdx.x;
    const int l = tid & 63, w = tid >> 6;           // w in 0..3
    const int l31 = l & 31, hi = l >> 5;
    const int hi4 = hi * 4;

    // staging decomposition
    const int krow = tid >> 4, kg = tid & 15;       // K: rows krow+16u, granule kg (16B)
    const int vd = tid >> 3, vg = tid & 7;          // V: d-rows vd+32u, granule vg

    // XCD swizzle: 512 blocks, 64 consecutive per XCD
    const int bid = blockIdx.x;
    const int swz = (bid & 7) * 64 + (bid >> 3);
    const int bh = swz >> 4, qt = swz & 15;
    const int b = bh >> 4, h = bh & 15;

    // Q fragments (B-operand): lane's q = l31; k = kc*16 + hi*8 + e. Scale folded (log2e).
    const int qrow = b * 2048 + qt * 128 + w * 32 + l31;
    const f16 qsc = (f16)(0.088388347648318447f * 1.44269504088896f);
    f16x8 qf[8];
#pragma unroll
    for (int kc = 0; kc < 8; ++kc) {
        f16x8 t0 = *(const f16x8*)(Qg + (size_t)qrow * 2048 + h * 128 + kc * 16 + hi * 8);
#pragma unroll
        for (int e = 0; e < 8; ++e) t0[e] = t0[e] * qsc;
        qf[kc] = t0;
    }

    f32x16 o[4] = {Z16, Z16, Z16, Z16};   // O[q=crow(r,hi)][d=dt*32+l31]
    float mrow = -3.0e38f, lrow = 0.0f;   // per-lane, q = l31 (dup across hi)

    const f16* Kbase = Kg + (size_t)(b * 2048) * 2048 + h * 128;
    const f16* Vbase = Vt + (size_t)(b * 2048 + h * 128) * 2048;

    u32x4 kst[4], vst[4];

#define LOADT(st) do {                                                                   \
    _Pragma("unroll")                                                                    \
    for (int u = 0; u < 4; ++u)                                                          \
        kst[u] = *(const u32x4*)(Kbase + (size_t)((st) + krow + u * 16) * 2048 + kg * 8);\
    _Pragma("unroll")                                                                    \
    for (int u = 0; u < 4; ++u)                                                          \
        vst[u] = *(const u32x4*)(Vbase + (size_t)(vd + u * 32) * 2048 + (st) + vg * 8);  \
} while (0)

#define WRITET(bf) do {                                                                  \
    _Pragma("unroll")                                                                    \
    for (int u = 0; u < 4; ++u) {                                                        \
        f16* p = &Kl[bf][(krow + u * 16) * 132 + kg * 8];                                \
        *(u32x2*)p       = (u32x2){kst[u].x, kst[u].y};                                  \
        *(u32x2*)(p + 4) = (u32x2){kst[u].z, kst[u].w};                                  \
    }                                                                                    \
    _Pragma("unroll")                                                                    \
    for (int u = 0; u < 4; ++u) {                                                        \
        f16* p = &Vl[bf][(vd + u * 32) * 68 + vg * 8];                                   \
        *(u32x2*)p       = (u32x2){vst[u].x, vst[u].y};                                  \
        *(u32x2*)(p + 4) = (u32x2){vst[u].z, vst[u].w};                                  \
    }                                                                                    \
} while (0)

    LOADT(0);
    WRITET(0);
    __syncthreads();

    int cur = 0;
    for (int t = 0; t < 32; ++t) {
        if (t < 31) LOADT((t + 1) * 64);            // issue early: hides under QK^T+softmax
        const f16* Kc = Kl[cur];
        const f16* Vc = Vl[cur];

        // ---- QK^T (swapped): P^T[s][q], lane holds q=l31, s = (r&3)+8*(r>>2)+4*hi (+32 for p1)
        f32x16 p0 = Z16, p1 = Z16;
        __builtin_amdgcn_s_setprio(1);
#pragma unroll
        for (int kc = 0; kc < 8; ++kc) {
            const int go = (kc * 2 + hi) * 8;
            const f16* kp0 = Kc + l31 * 132 + go;
            const f16* kp1 = Kc + (32 + l31) * 132 + go;
            const f16x4 a0 = *(const f16x4*)kp0, a1 = *(const f16x4*)(kp0 + 4);
            const f16x4 b0 = *(const f16x4*)kp1, b1 = *(const f16x4*)(kp1 + 4);
            const f16x8 k0 = __builtin_shufflevector(a0, a1, 0, 1, 2, 3, 4, 5, 6, 7);
            const f16x8 k1 = __builtin_shufflevector(b0, b1, 0, 1, 2, 3, 4, 5, 6, 7);
            p0 = MFMA32(k0, qf[kc], p0);
            p1 = MFMA32(k1, qf[kc], p1);
        }
        __builtin_amdgcn_s_setprio(0);

        // ---- online softmax (log2 domain): depth-5 max tree, then lane-pair combine
        float mt[16];
#pragma unroll
        for (int r = 0; r < 16; ++r) mt[r] = fmaxf(p0[r], p1[r]);
#pragma unroll
        for (int r = 0; r < 8; ++r) mt[r] = fmaxf(mt[r], mt[r + 8]);
#pragma unroll
        for (int r = 0; r < 4; ++r) mt[r] = fmaxf(mt[r], mt[r + 4]);
        float mx = fmaxf(fmaxf(mt[0], mt[1]), fmaxf(mt[2], mt[3]));
        mx = fswapmax(mx);

        if (!__all(mx <= mrow + 8.0f)) {
            const float mn = fmaxf(mrow, mx);
            const float cr = EX2(mrow - mn);
            mrow = mn;
            lrow *= cr;
            if (hi == 0) bnc[w][l31] = cr;
#pragma unroll
            for (int r = 0; r < 16; ++r) {
                const float crr = bnc[w][(r & 3) + 8 * (r >> 2) + 4 * hi];
                o[0][r] *= crr; o[1][r] *= crr; o[2][r] *= crr; o[3][r] *= crr;
            }
        }

        // exp2 (1 v_exp_f32 each) + depth-5 sum tree
        float st16[16];
#pragma unroll
        for (int r = 0; r < 16; ++r) {
            p0[r] = EX2(p0[r] - mrow);
            p1[r] = EX2(p1[r] - mrow);
            st16[r] = p0[r] + p1[r];
        }
#pragma unroll
        for (int r = 0; r < 8; ++r) st16[r] += st16[r + 8];
#pragma unroll
        for (int r = 0; r < 4; ++r) st16[r] += st16[r + 4];
        lrow += fswapsum((st16[0] + st16[1]) + (st16[2] + st16[3]));

        // ---- pack P -> A-frags from OWN lane values only (no cross-lane ops)
        // pf[ks] slot e holds P[q][s = ks*16 + hi*4 + (e&3) + (e>>2)*8]
        f16x8 pf[4];
#pragma unroll
        for (int ksl = 0; ksl < 2; ++ksl) {
            u32x4 w0 = {pk2(p0[8*ksl+0], p0[8*ksl+1]), pk2(p0[8*ksl+2], p0[8*ksl+3]),
                        pk2(p0[8*ksl+4], p0[8*ksl+5]), pk2(p0[8*ksl+6], p0[8*ksl+7])};
            pf[ksl] = __builtin_bit_cast(f16x8, w0);
            u32x4 w1 = {pk2(p1[8*ksl+0], p1[8*ksl+1]), pk2(p1[8*ksl+2], p1[8*ksl+3]),
                        pk2(p1[8*ksl+4], p1[8*ksl+5]), pk2(p1[8*ksl+6], p1[8*ksl+7])};
            pf[2 + ksl] = __builtin_bit_cast(f16x8, w1);
        }

        // write next tile into the other buffer (loads have landed by now)
        if (t < 31) WRITET(cur ^ 1);

        // ---- PV: O[q][d] += P[q][s] @ V[s][d]; V-frag gathered with the SAME slot map
        __builtin_amdgcn_s_setprio(1);
#pragma unroll
        for (int dt = 0; dt < 4; ++dt) {
            const f16* vrow = Vc + (dt * 32 + l31) * 68;
#pragma unroll
            for (int ks = 0; ks < 4; ++ks) {
                const f16x4 vlo = *(const f16x4*)(vrow + ks * 16 + hi4);
                const f16x4 vhi = *(const f16x4*)(vrow + ks * 16 + hi4 + 8);
                const f16x8 vf = __builtin_shufflevector(vlo, vhi, 0, 1, 2, 3, 4, 5, 6, 7);
                o[dt] = MFMA32(pf[ks], vf, o[dt]);
            }
        }
        __builtin_amdgcn_s_setprio(0);

        __syncthreads();
        cur ^= 1;
    }
#undef LOADT
#undef WRITET

    // ---- epilogue: normalize (1/l broadcast by q-row), write ctx [b*2048+t][h*128+d]
    const float inv = 1.0f / lrow;
    if (hi == 0) bnc[w][l31] = inv;
#pragma unroll
    for (int r = 0; r < 16; ++r) {
        const int qq = (r & 3) + 8 * (r >> 2) + 4 * hi;
        const float ir = bnc[w][qq];
        const size_t row = (size_t)(b * 2048 + qt * 128 + w * 32 + qq);
#pragma unroll
        for (int dt = 0; dt < 4; ++dt)
            Og[row * 2048 + h * 128 + dt * 32 + l31] = (f16)(o[dt][r] * ir);
    }
}

extern "C" void kernel_launch(void* const* d_in, const int* in_sizes, int n_in,
                              void* d_out, int out_size, void* d_ws, size_t ws_size,
                              hipStream_t stream) {
    const float* hs = (const float*)d_in[0];
    const float* es = (const float*)d_in[1];
    const float* Wq = (const float*)d_in[2];
    const float* Wk = (const float*)d_in[3];
    const float* Wv = (const float*)d_in[4];
    const float* Wo = (const float*)d_in[5];
    const float* cq = (const float*)d_in[6];
    const float* sq = (const float*)d_in[7];
    const float* ck = (const float*)d_in[8];
    const float* sk = (const float*)d_in[9];
    float* out = (float*)d_out;

    f16* hs16 = (f16*)d_ws;
    f16* es16 = hs16 + 8388608;
    f16* Wq16 = es16 + 8388608;
    f16* Wk16 = Wq16 + 4194304;
    f16* Wv16 = Wk16 + 4194304;
    f16* Wo16 = Wv16 + 4194304;
    f16* Q16  = Wo16 + 4194304;
    f16* K16  = Q16 + 8388608;
    f16* Vt16 = K16 + 8388608;
    f16* ctx16 = hs16;   // reuse (hs16 dead after Q-GEMM)

    const dim3 tB(256);
    cvt_all<<<dim3(16384), tB, 0, stream>>>(hs, es, Wq, Wk, Wv, Wo, hs16);

    gemm16<4><<<dim3(512), tB, 0, stream>>>(hs16, Wq16, Q16, 4096, 2048, 2048, cq, sq);
    gemm16<4><<<dim3(512), tB, 0, stream>>>(es16, Wk16, K16, 4096, 2048, 2048, ck, sk);
    gemm16<3><<<dim3(512), tB, 0, stream>>>(Wv16, es16, Vt16, 2048, 4096, 2048, nullptr, nullptr);

    attn16<<<dim3(512), tB, 0, stream>>>(Q16, K16, Vt16, ctx16);

    gemm16<2><<<dim3(512), tB, 0, stream>>>(ctx16, Wo16, out, 4096, 2048, 2048, nullptr, nullptr);
}